// Round 9
// baseline (806.894 us; speedup 1.0000x reference)
//
#include <hip/hip_runtime.h>
#include <math.h>

#define B_ 4
#define L_ 2048
#define HD_ 1024
#define H_ 16
#define VD_ 64
#define M_ 128
#define M2_ 256
#define RIDGE_ 0.01f
#define SCALE_ 0.08838834764831845f   // 1/sqrt(128)

typedef unsigned short u16;
typedef __attribute__((ext_vector_type(8))) short short8;
typedef __attribute__((ext_vector_type(4))) float floatx4;

__device__ __forceinline__ u16 f2bf(float x) {
  unsigned u = __float_as_uint(x);
  unsigned r = u + 0x7fff + ((u >> 16) & 1);
  return (u16)(r >> 16);
}
__device__ __forceinline__ float bf2f(u16 h) {
  return __uint_as_float(((unsigned)h) << 16);
}
__device__ __forceinline__ void gload_lds16(const u16* g, u16* l) {
  __builtin_amdgcn_global_load_lds(
      (const __attribute__((address_space(1))) unsigned int*)g,
      (__attribute__((address_space(3))) unsigned int*)l, 16, 0, 0);
}
__device__ __forceinline__ void split4(float4 f, ushort4* h, float4* r) {
  h->x = f2bf(f.x); h->y = f2bf(f.y); h->z = f2bf(f.z); h->w = f2bf(f.w);
  r->x = f.x - bf2f(h->x); r->y = f.y - bf2f(h->y);
  r->z = f.z - bf2f(h->z); r->w = f.w - bf2f(h->w);
}
// counted vmcnt (never 0 in loop) + raw barrier with compiler fences:
// loads for the NEXT tile stay in flight across the barrier (T3/T4).
#define WAITVM(N) asm volatile("s_waitcnt vmcnt(" #N ")" ::: "memory")
__device__ __forceinline__ void barf() {
  asm volatile("" ::: "memory");
  __builtin_amdgcn_s_barrier();
  asm volatile("" ::: "memory");
}
// bijective XCD swizzle: consecutive remapped ids (same XCD) walk x within a
// y-row, so blocks sharing an A-panel co-reside on one XCD's L2. nwg%8==0.
__device__ __forceinline__ void swz2d(int* bx, int* by) {
  int gx = gridDim.x;
  int nwg = gx * gridDim.y;
  int orig = (*by) * gx + (*bx);
  int wg = (orig & 7) * (nwg >> 3) + (orig >> 3);
  *bx = wg % gx;
  *by = wg / gx;
}

// ---------------- fp32 -> bf16 hi/lo split ---------------------------------
__global__ __launch_bounds__(256) void cvt_split_kernel(
    const float* __restrict__ src, u16* __restrict__ hi, u16* __restrict__ lo, int n4)
{
  int i = blockIdx.x * 256 + threadIdx.x;
  if (i < n4) {
    float4 f = ((const float4*)src)[i];
    ushort4 hv; float4 r;
    split4(f, &hv, &r);
    ushort4 lv = {f2bf(r.x), f2bf(r.y), f2bf(r.z), f2bf(r.w)};
    ((ushort4*)hi)[i] = hv;
    ((ushort4*)lo)[i] = lv;
  }
}

// ---------------- bf16 MFMA GEMM (counted-vmcnt pipeline), C = A * B^T -----
__global__ __launch_bounds__(256) void mfma_nt(
    const u16* __restrict__ A0, const u16* __restrict__ B0,
    float* __restrict__ C, int Ndim, int Kdim, int ldA, int ldB,
    const float* __restrict__ bias, const float* __restrict__ mask)
{
  __shared__ __align__(16) u16 a_sm[2][4096];
  __shared__ __align__(16) u16 b_sm[2][4096];
  const int tid = threadIdx.x;
  const int wave = tid >> 6, lane = tid & 63;
  int bx = blockIdx.x, by = blockIdx.y;
  swz2d(&bx, &by);
  const int m0 = by * 128, n0 = bx * 128;
  const int wrow = (wave >> 1) * 64, wcol = (wave & 1) * 64;
  const int fm = lane & 15, q = lane >> 4;
  const int lofs = wave * 1024;

  floatx4 acc[4][4];
#pragma unroll
  for (int i = 0; i < 4; ++i)
#pragma unroll
    for (int j = 0; j < 4; ++j) acc[i][j] = (floatx4){0.f, 0.f, 0.f, 0.f};

  const u16* Ag0 = A0 + (long)(m0 + lane) * ldA + wave * 8;
  const u16* Ag1 = A0 + (long)(m0 + 64 + lane) * ldA + wave * 8;
  const u16* Bg0 = B0 + (long)(n0 + lane) * ldB + wave * 8;
  const u16* Bg1 = B0 + (long)(n0 + 64 + lane) * ldB + wave * 8;

  auto stage = [&](int d, int k0) {
    gload_lds16(Ag0 + k0, &a_sm[d][lofs]);
    gload_lds16(Ag1 + k0, &a_sm[d][lofs + 512]);
    gload_lds16(Bg0 + k0, &b_sm[d][lofs]);
    gload_lds16(Bg1 + k0, &b_sm[d][lofs + 512]);
  };
  auto compute = [&](int d) {
    short8 af[4], bfv[4];
#pragma unroll
    for (int i = 0; i < 4; ++i)
      af[i] = *(const short8*)&a_sm[d][(q * 128 + wrow + i * 16 + fm) * 8];
#pragma unroll
    for (int j = 0; j < 4; ++j)
      bfv[j] = *(const short8*)&b_sm[d][(q * 128 + wcol + j * 16 + fm) * 8];
    __builtin_amdgcn_s_setprio(1);
#pragma unroll
    for (int i = 0; i < 4; ++i)
#pragma unroll
      for (int j = 0; j < 4; ++j)
        acc[i][j] = __builtin_amdgcn_mfma_f32_16x16x32_bf16(af[i], bfv[j], acc[i][j], 0, 0, 0);
    __builtin_amdgcn_s_setprio(0);
  };

  stage(0, 0);
  stage(1, 32);
  for (int k = 0; k + 64 < Kdim; k += 64) {
    WAITVM(4); barf();
    compute(0);
    barf();
    stage(0, k + 64);
    WAITVM(4); barf();
    compute(1);
    barf();
    stage(1, k + 96);
  }
  WAITVM(4); barf();
  compute(0);
  barf();
  WAITVM(0); barf();
  compute(1);

  const int colb = n0 + wcol + fm;
  const int rbase = m0 + wrow + (lane >> 4) * 4;
#pragma unroll
  for (int j = 0; j < 4; ++j) {
    int cg = colb + j * 16;
    float bb = bias ? bias[cg] : 0.f;
#pragma unroll
    for (int i = 0; i < 4; ++i) {
#pragma unroll
      for (int r = 0; r < 4; ++r) {
        int row = rbase + i * 16 + r;
        float val = acc[i][j][r];
        if (bias) val = (val + bb) * mask[row];
        C[(long)row * Ndim + cg] = val;
      }
    }
  }
}

// ---------------- uniform bf16x3 MFMA GEMM (q,k columns only) ---------------
__global__ __launch_bounds__(256) void mfma_qk3(
    const u16* __restrict__ Ah, const u16* __restrict__ Al,
    const u16* __restrict__ Bh, const u16* __restrict__ Bl,
    float* __restrict__ Cq, float* __restrict__ Ck)
{
  __shared__ __align__(16) u16 ah_sm[2][4096], al_sm[2][4096];
  __shared__ __align__(16) u16 bh_sm[2][4096], bl_sm[2][4096];
  const int tid = threadIdx.x;
  const int wave = tid >> 6, lane = tid & 63;
  int bx = blockIdx.x, by = blockIdx.y;
  swz2d(&bx, &by);
  const int m0 = by * 128, n0 = bx * 128;
  const int wrow = (wave >> 1) * 64, wcol = (wave & 1) * 64;
  const int fm = lane & 15, q = lane >> 4;
  const int lofs = wave * 1024;

  floatx4 acc[4][4];
#pragma unroll
  for (int i = 0; i < 4; ++i)
#pragma unroll
    for (int j = 0; j < 4; ++j) acc[i][j] = (floatx4){0.f, 0.f, 0.f, 0.f};

  const long a0o = (long)(m0 + lane) * 1024 + wave * 8;
  const long a1o = (long)(m0 + 64 + lane) * 1024 + wave * 8;
  const long b0o = (long)(n0 + lane) * 1024 + wave * 8;
  const long b1o = (long)(n0 + 64 + lane) * 1024 + wave * 8;

  auto stage = [&](int d, int k0) {
    gload_lds16(Ah + a0o + k0, &ah_sm[d][lofs]);
    gload_lds16(Ah + a1o + k0, &ah_sm[d][lofs + 512]);
    gload_lds16(Al + a0o + k0, &al_sm[d][lofs]);
    gload_lds16(Al + a1o + k0, &al_sm[d][lofs + 512]);
    gload_lds16(Bh + b0o + k0, &bh_sm[d][lofs]);
    gload_lds16(Bh + b1o + k0, &bh_sm[d][lofs + 512]);
    gload_lds16(Bl + b0o + k0, &bl_sm[d][lofs]);
    gload_lds16(Bl + b1o + k0, &bl_sm[d][lofs + 512]);
  };
  auto compute = [&](int d) {
    short8 afh[4], afl[4], bfh[4], bfl[4];
#pragma unroll
    for (int i = 0; i < 4; ++i) {
      afh[i] = *(const short8*)&ah_sm[d][(q * 128 + wrow + i * 16 + fm) * 8];
      afl[i] = *(const short8*)&al_sm[d][(q * 128 + wrow + i * 16 + fm) * 8];
    }
#pragma unroll
    for (int j = 0; j < 4; ++j) {
      bfh[j] = *(const short8*)&bh_sm[d][(q * 128 + wcol + j * 16 + fm) * 8];
      bfl[j] = *(const short8*)&bl_sm[d][(q * 128 + wcol + j * 16 + fm) * 8];
    }
    __builtin_amdgcn_s_setprio(1);
#pragma unroll
    for (int i = 0; i < 4; ++i)
#pragma unroll
      for (int j = 0; j < 4; ++j) {
        acc[i][j] = __builtin_amdgcn_mfma_f32_16x16x32_bf16(afh[i], bfh[j], acc[i][j], 0, 0, 0);
        acc[i][j] = __builtin_amdgcn_mfma_f32_16x16x32_bf16(afl[i], bfh[j], acc[i][j], 0, 0, 0);
        acc[i][j] = __builtin_amdgcn_mfma_f32_16x16x32_bf16(afh[i], bfl[j], acc[i][j], 0, 0, 0);
      }
    __builtin_amdgcn_s_setprio(0);
  };

  stage(0, 0);
  stage(1, 32);
  for (int k = 0; k + 64 < 1024; k += 64) {
    WAITVM(8); barf();
    compute(0);
    barf();
    stage(0, k + 64);
    WAITVM(8); barf();
    compute(1);
    barf();
    stage(1, k + 96);
  }
  WAITVM(8); barf();
  compute(0);
  barf();
  WAITVM(0); barf();
  compute(1);

  float* Cp; int cb;
  if (n0 < 1024) { Cp = Cq; cb = n0; }
  else           { Cp = Ck; cb = n0 - 1024; }
  const int colb = cb + wcol + fm;
  const int rbase = m0 + wrow + (lane >> 4) * 4;
#pragma unroll
  for (int j = 0; j < 4; ++j) {
    int cg = colb + j * 16;
#pragma unroll
    for (int i = 0; i < 4; ++i)
#pragma unroll
      for (int r = 0; r < 4; ++r)
        Cp[(long)(rbase + i * 16 + r) * 1024 + cg] = acc[i][j][r];
  }
}

// ---------------- RFF(k): transposed bf16 hi/lo into pkT --------------------
__global__ __launch_bounds__(256) void rff_k_t(
    const float* __restrict__ src, const float* __restrict__ mask,
    const float* __restrict__ rffW, const float* __restrict__ rffb,
    u16* __restrict__ pkh, u16* __restrict__ pkl, int b0)
{
  __shared__ __align__(16) float w_lds[64][132];
  __shared__ __align__(16) float x_lds[64][68];
  __shared__ float b_lds[128];
  const int l0 = blockIdx.x * 64;
  const int h = blockIdx.y, b = b0 + blockIdx.z;
  const int zloc = blockIdx.z * 16 + h;
  const int tid = threadIdx.x;

  const float* wsrc = rffW + h * 8192;
  for (int f = tid * 4; f < 8192; f += 1024) {
    int d = f >> 7, m = f & 127;
    *(float4*)&w_lds[d][m] = *(const float4*)&wsrc[f];
  }
  if (tid < 128) b_lds[tid] = rffb[h * 128 + tid];
  {
    int r = tid >> 2, c0 = (tid & 3) * 16;
    const float* srow = src + (long)(b * L_ + l0 + r) * 1024 + h * VD_ + c0;
    *(float4*)&x_lds[r][c0 + 0]  = *(const float4*)(srow + 0);
    *(float4*)&x_lds[r][c0 + 4]  = *(const float4*)(srow + 4);
    *(float4*)&x_lds[r][c0 + 8]  = *(const float4*)(srow + 8);
    *(float4*)&x_lds[r][c0 + 12] = *(const float4*)(srow + 12);
  }
  __syncthreads();

  const int ty = tid >> 4, tx = tid & 15;
  float acc[4][8];
  {
    float4 bb0 = *(const float4*)&b_lds[4 * tx];
    float4 bb1 = *(const float4*)&b_lds[4 * tx + 64];
#pragma unroll
    for (int i = 0; i < 4; ++i) {
      acc[i][0] = bb0.x; acc[i][1] = bb0.y; acc[i][2] = bb0.z; acc[i][3] = bb0.w;
      acc[i][4] = bb1.x; acc[i][5] = bb1.y; acc[i][6] = bb1.z; acc[i][7] = bb1.w;
    }
  }
#pragma unroll 8
  for (int kk = 0; kk < 64; ++kk) {
    float4 w0 = *(const float4*)&w_lds[kk][4 * tx];
    float4 w1 = *(const float4*)&w_lds[kk][4 * tx + 64];
    float xv[4];
#pragma unroll
    for (int i = 0; i < 4; ++i) xv[i] = x_lds[4 * ty + i][kk];
#pragma unroll
    for (int i = 0; i < 4; ++i) {
      acc[i][0] = fmaf(xv[i], w0.x, acc[i][0]);
      acc[i][1] = fmaf(xv[i], w0.y, acc[i][1]);
      acc[i][2] = fmaf(xv[i], w0.z, acc[i][2]);
      acc[i][3] = fmaf(xv[i], w0.w, acc[i][3]);
      acc[i][4] = fmaf(xv[i], w1.x, acc[i][4]);
      acc[i][5] = fmaf(xv[i], w1.y, acc[i][5]);
      acc[i][6] = fmaf(xv[i], w1.z, acc[i][6]);
      acc[i][7] = fmaf(xv[i], w1.w, acc[i][7]);
    }
  }
  float fi[4];
#pragma unroll
  for (int i = 0; i < 4; ++i) fi[i] = SCALE_ * mask[b * L_ + l0 + 4 * ty + i];
  float cvv[4][8], svv[4][8];
#pragma unroll
  for (int i = 0; i < 4; ++i)
#pragma unroll
    for (int jj = 0; jj < 8; ++jj) {
      float sv, cv;
      sincosf(acc[i][jj], &sv, &cv);
      cvv[i][jj] = cv * fi[i];
      svv[i][jj] = sv * fi[i];
    }
  const long lbase = l0 + 4 * ty;
  const long zbase = (long)zloc * 655360;
#pragma unroll
  for (int jj = 0; jj < 8; ++jj) {
    int mcol = (jj < 4) ? (4 * tx + jj) : (64 + 4 * tx + (jj - 4));
    ushort4 h4, l4;
    h4.x = f2bf(cvv[0][jj]); l4.x = f2bf(cvv[0][jj] - bf2f(h4.x));
    h4.y = f2bf(cvv[1][jj]); l4.y = f2bf(cvv[1][jj] - bf2f(h4.y));
    h4.z = f2bf(cvv[2][jj]); l4.z = f2bf(cvv[2][jj] - bf2f(h4.z));
    h4.w = f2bf(cvv[3][jj]); l4.w = f2bf(cvv[3][jj] - bf2f(h4.w));
    long base = zbase + (long)mcol * 2048 + lbase;
    *(ushort4*)&pkh[base] = h4;
    *(ushort4*)&pkl[base] = l4;
    ushort4 hs, ls;
    hs.x = f2bf(svv[0][jj]); ls.x = f2bf(svv[0][jj] - bf2f(hs.x));
    hs.y = f2bf(svv[1][jj]); ls.y = f2bf(svv[1][jj] - bf2f(hs.y));
    hs.z = f2bf(svv[2][jj]); ls.z = f2bf(svv[2][jj] - bf2f(hs.z));
    hs.w = f2bf(svv[3][jj]); ls.w = f2bf(svv[3][jj] - bf2f(hs.w));
    long base2 = zbase + (long)(mcol + 128) * 2048 + lbase;
    *(ushort4*)&pkh[base2] = hs;
    *(ushort4*)&pkl[base2] = ls;
  }
}

// ---------------- masked V transpose into pkT rows 256..319 -----------------
__global__ __launch_bounds__(256) void vt_kernel(
    const float* __restrict__ v, const float* __restrict__ mask,
    u16* __restrict__ pkh, u16* __restrict__ pkl, int b0)
{
  __shared__ float t[128][65];
  const int z = blockIdx.y;
  const int b = b0 + (z >> 4), h = z & 15;
  const int l0 = blockIdx.x * 128;
  const int tid = threadIdx.x;
  const int d = tid & 63, lg = tid >> 6;
  for (int i = 0; i < 128; i += 4) {
    int ll = i + lg;
    float mv = mask[b * L_ + l0 + ll];
    t[ll][d] = v[(long)(b * L_ + l0 + ll) * 1024 + h * 64 + d] * mv;
  }
  __syncthreads();
  const int d2 = tid >> 2, lofs = (tid & 3) * 32;
  long base = (long)z * 655360 + (long)(256 + d2) * 2048 + l0 + lofs;
  for (int j = 0; j < 32; j += 4) {
    float f0 = t[lofs + j + 0][d2], f1 = t[lofs + j + 1][d2];
    float f2 = t[lofs + j + 2][d2], f3 = t[lofs + j + 3][d2];
    ushort4 hv, lv;
    hv.x = f2bf(f0); lv.x = f2bf(f0 - bf2f(hv.x));
    hv.y = f2bf(f1); lv.y = f2bf(f1 - bf2f(hv.y));
    hv.z = f2bf(f2); lv.z = f2bf(f2 - bf2f(hv.z));
    hv.w = f2bf(f3); lv.w = f2bf(f3 - bf2f(hv.w));
    *(ushort4*)&pkh[base + j] = hv;
    *(ushort4*)&pkl[base + j] = lv;
  }
}

// ---------------- batched bf16x3 MFMA: [G-lower|T] partials, K-split x2 -----
// G is symmetric and only its lower triangle + diag are consumed downstream
// (chol reads row>=col; tri_solve fwd reads L lower, bwd reads transposed
// lower; invD diag). Skip the 2 strictly-upper 128x64 blocks per (kc,z).
__global__ __launch_bounds__(256) void mfma_gt(
    const u16* __restrict__ pkh, const u16* __restrict__ pkl,
    float* __restrict__ Gp, float* __restrict__ Tp, int bh0)
{
  __shared__ __align__(16) u16 ah_sm[2][4096], al_sm[2][4096];
  __shared__ __align__(16) u16 bh_sm[2][2048], bl_sm[2][2048];
  const int tid = threadIdx.x;
  const int wave = tid >> 6, lane = tid & 63;
  // grid = (8 combos, 2 kc, 32 z); bijective XCD swizzle over 512 wgs
  int orig = (blockIdx.z * gridDim.y + blockIdx.y) * gridDim.x + blockIdx.x;
  int wg = (orig & 7) * 64 + (orig >> 3);
  const int cx = wg & 7;
  const int rr = wg >> 3;
  const int kc = rr & 1;
  const int z = rr >> 1;
  int mt, n0;
  if (cx < 3) { mt = 0; n0 = (cx == 2) ? 256 : cx * 64; }
  else        { mt = 1; n0 = (cx - 3) * 64; }
  const int m0 = mt * 128;
  const int wrow = (wave >> 1) * 64, wcol = (wave & 1) * 32;
  const int fm = lane & 15, q = lane >> 4;
  const long batch = (long)z * 655360;
  const u16* Ahp = pkh + batch;
  const u16* Alp = pkl + batch;
  const int lofsA = wave * 1024;
  const int lofsB = wave * 512;

  floatx4 acc[4][2];
#pragma unroll
  for (int i = 0; i < 4; ++i)
#pragma unroll
    for (int j = 0; j < 2; ++j) acc[i][j] = (floatx4){0.f, 0.f, 0.f, 0.f};

  const long a0o = (long)(m0 + lane) * 2048 + wave * 8;
  const long a1o = (long)(m0 + 64 + lane) * 2048 + wave * 8;
  const long b0o = (long)(n0 + lane) * 2048 + wave * 8;

  auto stage = [&](int d, int k0) {
    gload_lds16(Ahp + a0o + k0, &ah_sm[d][lofsA]);
    gload_lds16(Ahp + a1o + k0, &ah_sm[d][lofsA + 512]);
    gload_lds16(Alp + a0o + k0, &al_sm[d][lofsA]);
    gload_lds16(Alp + a1o + k0, &al_sm[d][lofsA + 512]);
    gload_lds16(Ahp + b0o + k0, &bh_sm[d][lofsB]);
    gload_lds16(Alp + b0o + k0, &bl_sm[d][lofsB]);
  };
  auto compute = [&](int d) {
    short8 afh[4], afl[4], bfh[2], bfl[2];
#pragma unroll
    for (int i = 0; i < 4; ++i) {
      afh[i] = *(const short8*)&ah_sm[d][(q * 128 + wrow + i * 16 + fm) * 8];
      afl[i] = *(const short8*)&al_sm[d][(q * 128 + wrow + i * 16 + fm) * 8];
    }
#pragma unroll
    for (int j = 0; j < 2; ++j) {
      bfh[j] = *(const short8*)&bh_sm[d][(q * 64 + wcol + j * 16 + fm) * 8];
      bfl[j] = *(const short8*)&bl_sm[d][(q * 64 + wcol + j * 16 + fm) * 8];
    }
    __builtin_amdgcn_s_setprio(1);
#pragma unroll
    for (int i = 0; i < 4; ++i)
#pragma unroll
      for (int j = 0; j < 2; ++j) {
        acc[i][j] = __builtin_amdgcn_mfma_f32_16x16x32_bf16(afh[i], bfh[j], acc[i][j], 0, 0, 0);
        acc[i][j] = __builtin_amdgcn_mfma_f32_16x16x32_bf16(afl[i], bfh[j], acc[i][j], 0, 0, 0);
        acc[i][j] = __builtin_amdgcn_mfma_f32_16x16x32_bf16(afh[i], bfl[j], acc[i][j], 0, 0, 0);
      }
    __builtin_amdgcn_s_setprio(0);
  };

  const int kbeg = kc * 1024, kend = kbeg + 1024;
  stage(0, kbeg);
  stage(1, kbeg + 32);
  for (int k = kbeg; k + 64 < kend; k += 64) {
    WAITVM(6); barf();
    compute(0);
    barf();
    stage(0, k + 64);
    WAITVM(6); barf();
    compute(1);
    barf();
    stage(1, k + 96);
  }
  WAITVM(6); barf();
  compute(0);
  barf();
  WAITVM(0); barf();
  compute(1);

  const int bh = bh0 + z;
  float* Gb = Gp + (long)kc * 4194304;
  float* Tb = Tp + (long)kc * 1048576;
  const int rbase = m0 + wrow + (lane >> 4) * 4;
#pragma unroll
  for (int j = 0; j < 2; ++j) {
    int col = n0 + wcol + j * 16 + fm;
#pragma unroll
    for (int i = 0; i < 4; ++i)
#pragma unroll
      for (int r = 0; r < 4; ++r) {
        int row = rbase + i * 16 + r;
        float val = acc[i][j][r];
        if (n0 < 256) Gb[(long)bh * 65536 + (long)row * 256 + col] = val;
        else Tb[(long)bh * 16384 + (long)row * 64 + (col - 256)] = val;
      }
  }
}

// ---------------- reduce K-split partials into final G, T -------------------
// (T must be reduced BEFORE chol_rffq writes phiq: Tp aliases phiq_lo.)
__global__ __launch_bounds__(256) void reduce_gt_kernel(
    const float* __restrict__ Gp, float* __restrict__ G,
    const float* __restrict__ Tp, float* __restrict__ T)
{
  long i = (long)blockIdx.x * 256 + threadIdx.x;  // float4 index
  if (i < 1048576) {
    float4 a = ((const float4*)Gp)[i];
    float4 b = ((const float4*)(Gp + 4194304))[i];
    float4 o = {a.x + b.x, a.y + b.y, a.z + b.z, a.w + b.w};
    ((float4*)G)[i] = o;
  } else {
    long j = i - 1048576;
    float4 a = ((const float4*)Tp)[j];
    float4 b = ((const float4*)(Tp + 1048576))[j];
    float4 o = {a.x + b.x, a.y + b.y, a.z + b.z, a.w + b.w};
    ((float4*)T)[j] = o;
  }
}

// ---------------- batched bf16x3 MFMA: oh = PhiQ @ Wt^T (bf16 out) ----------
__global__ __launch_bounds__(256) void mfma_out_k(
    const u16* __restrict__ ph, const u16* __restrict__ pl,
    const u16* __restrict__ wth, const u16* __restrict__ wtl,
    u16* __restrict__ oh)
{
  __shared__ __align__(16) u16 ah_sm[2][4096], al_sm[2][4096];
  __shared__ __align__(16) u16 bh_sm[2][2048], bl_sm[2][2048];
  const int tid = threadIdx.x;
  const int wave = tid >> 6, lane = tid & 63;
  int bx = blockIdx.x, by = blockIdx.y;
  swz2d(&bx, &by);
  const int bh = by;
  const int b = bh >> 4, h = bh & 15;
  const int l0 = bx * 128;
  const int wrow = (wave >> 1) * 64, wcol = (wave & 1) * 32;
  const int fm = lane & 15, q = lane >> 4;
  const u16* Ahp = ph + (long)bh * 524288 + (long)l0 * 256;
  const u16* Alp = pl + (long)bh * 524288 + (long)l0 * 256;
  const u16* Bhp = wth + (long)bh * 16384;
  const u16* Blp = wtl + (long)bh * 16384;
  const int lofsA = wave * 1024;
  const int lofsB = wave * 512;

  floatx4 acc[4][2];
#pragma unroll
  for (int i = 0; i < 4; ++i)
#pragma unroll
    for (int j = 0; j < 2; ++j) acc[i][j] = (floatx4){0.f, 0.f, 0.f, 0.f};

  const long a0o = (long)lane * 256 + wave * 8;
  const long a1o = (long)(64 + lane) * 256 + wave * 8;
  const long b0o = (long)lane * 256 + wave * 8;

  auto stage = [&](int d, int k0) {
    gload_lds16(Ahp + a0o + k0, &ah_sm[d][lofsA]);
    gload_lds16(Ahp + a1o + k0, &ah_sm[d][lofsA + 512]);
    gload_lds16(Alp + a0o + k0, &al_sm[d][lofsA]);
    gload_lds16(Alp + a1o + k0, &al_sm[d][lofsA + 512]);
    gload_lds16(Bhp + b0o + k0, &bh_sm[d][lofsB]);
    gload_lds16(Blp + b0o + k0, &bl_sm[d][lofsB]);
  };
  auto compute = [&](int d) {
    short8 afh[4], afl[4], bfh[2], bfl[2];
#pragma unroll
    for (int i = 0; i < 4; ++i) {
      afh[i] = *(const short8*)&ah_sm[d][(q * 128 + wrow + i * 16 + fm) * 8];
      afl[i] = *(const short8*)&al_sm[d][(q * 128 + wrow + i * 16 + fm) * 8];
    }
#pragma unroll
    for (int j = 0; j < 2; ++j) {
      bfh[j] = *(const short8*)&bh_sm[d][(q * 64 + wcol + j * 16 + fm) * 8];
      bfl[j] = *(const short8*)&bl_sm[d][(q * 64 + wcol + j * 16 + fm) * 8];
    }
    __builtin_amdgcn_s_setprio(1);
#pragma unroll
    for (int i = 0; i < 4; ++i)
#pragma unroll
      for (int j = 0; j < 2; ++j) {
        acc[i][j] = __builtin_amdgcn_mfma_f32_16x16x32_bf16(afh[i], bfh[j], acc[i][j], 0, 0, 0);
        acc[i][j] = __builtin_amdgcn_mfma_f32_16x16x32_bf16(afl[i], bfh[j], acc[i][j], 0, 0, 0);
        acc[i][j] = __builtin_amdgcn_mfma_f32_16x16x32_bf16(afh[i], bfl[j], acc[i][j], 0, 0, 0);
      }
    __builtin_amdgcn_s_setprio(0);
  };

  stage(0, 0);
  stage(1, 32);
  for (int k = 0; k + 64 < 256; k += 64) {
    WAITVM(6); barf();
    compute(0);
    barf();
    stage(0, k + 64);
    WAITVM(6); barf();
    compute(1);
    barf();
    stage(1, k + 96);
  }
  WAITVM(6); barf();
  compute(0);
  barf();
  WAITVM(0); barf();
  compute(1);

  const int rbase = l0 + wrow + (lane >> 4) * 4;
#pragma unroll
  for (int j = 0; j < 2; ++j) {
    int col = h * 64 + wcol + j * 16 + fm;
#pragma unroll
    for (int i = 0; i < 4; ++i)
#pragma unroll
      for (int r = 0; r < 4; ++r)
        oh[(long)(b * L_ + rbase + i * 16 + r) * 1024 + col] = f2bf(acc[i][j][r]);
  }
}

// ---------------- fused: out-of-core chol (0-63) + rff(q) (64-2111) + Wo cvt
// chol v2: LDS-routed panel dataflow. Two fixed-role LDS buffers:
//   pa [256][20] = A column-panel staging (filled by previous panel's C phase
//                  for the J==p+1 column; prologue stages col 0 from global)
//   pl [256][20] = L of current panel (written by B2, read by C)
// This removes the per-panel B1 global re-read and the diag global read; C's
// global pair-loads are software-pipelined (prefetch next pi while computing).
// Row stride 20 floats keeps rows 16B-aligned for ds_read_b128.
__global__ __launch_bounds__(512) void chol_rffq_wo_kernel(
    float* __restrict__ Gw,
    const float* __restrict__ qsrc,
    const float* __restrict__ rffW, const float* __restrict__ rffb,
    u16* __restrict__ ph, u16* __restrict__ pl_out,
    const float* __restrict__ Wo, u16* __restrict__ wo_hi)
{
  extern __shared__ float sm[];
  const int bx = blockIdx.x;
  const int tid = threadIdx.x;

  if (bx < 64) {
    float* pa   = sm;            // [256][20] = 5120 floats
    float* plds = sm + 5120;     // [256][20] = 5120 floats
    float* invD = sm + 10240;    // [16][20]  = 320 floats
    float* Gb = Gw + (long)bx * 65536;

    // prologue: stage A(:, col-block 0) into pa
    for (int f = tid; f < 4096; f += 512) {
      int rr = f >> 4, cc = f & 15;
      pa[rr * 20 + cc] = Gb[rr * 256 + cc];
    }
    __syncthreads();

    for (int p = 0; p < 16; ++p) {
      // A: wave 0 factors diag block (from pa LDS), computes invD
      if (tid < 64) {
        const int i = tid & 15;
        float r[16];
#pragma unroll
        for (int k = 0; k < 16; ++k) r[k] = pa[(16 * p + i) * 20 + k];
        r[i] += RIDGE_;
#pragma unroll
        for (int j = 0; j < 16; ++j) {
          float dj = __shfl(r[j], j);
          float dinv = 1.0f / sqrtf(dj);
          r[j] *= dinv;
          float Lij = r[j];
#pragma unroll
          for (int k = j + 1; k < 16; ++k) {
            float Lkj = __shfl(r[j], k);
            r[k] = fmaf(-Lij, Lkj, r[k]);
          }
        }
        float x[16];
#pragma unroll
        for (int j = 0; j < 16; ++j) {
          float s = (i == j) ? 1.0f : 0.0f;
#pragma unroll
          for (int k = 0; k < j; ++k) {
            float Ljk = __shfl(r[k], j);
            s = fmaf(-Ljk, x[k], s);
          }
          float Ljj = __shfl(r[j], j);
          x[j] = s / Ljj;
        }
        if (tid < 16) {
#pragma unroll
          for (int j = 0; j < 16; ++j) {
            invD[j * 20 + tid] = x[j];
            Gb[(16 * p + j) * 256 + 16 * p + tid] = x[j];  // diag slot <- invD
          }
        }
      }
      __syncthreads();

      const int nIb = 15 - p;
      if (nIb == 0) break;
      const int nrows = nIb * 16;
      const int r0 = 16 * (p + 1);

      // B2: L(I,p) = A(I,p) * invD^T  (pa -> plds + G, single pass)
#pragma unroll
      for (int s = 0; s < 8; ++s) {
        int f = tid + s * 512;
        if (f < nrows * 16) {
          int rr = f >> 4, j = f & 15;
          const float* arow = &pa[(r0 + rr) * 20];
          const float* dcol = &invD[j * 20];
          float s2 = 0.f;
#pragma unroll
          for (int k4 = 0; k4 < 16; k4 += 4) {
            float4 a4 = *(const float4*)&arow[k4];
            float4 d4 = *(const float4*)&dcol[k4];
            s2 = fmaf(a4.x, d4.x, s2);
            s2 = fmaf(a4.y, d4.y, s2);
            s2 = fmaf(a4.z, d4.z, s2);
            s2 = fmaf(a4.w, d4.w, s2);
          }
          plds[(r0 + rr) * 20 + j] = s2;
          Gb[(long)(r0 + rr) * 256 + 16 * p + j] = s2;
        }
      }
      __syncthreads();

      // C: trailing update; J == p+1 column goes to pa (next panel's A),
      // other columns read+write global. Pair loads software-pipelined.
      const int npairs = nIb * (nIb + 1) / 2;
      const int g = tid >> 4, t = tid & 15;
      const int tx = t & 3, ty = t >> 2;

      int IA = 0, JA = 0;
      float c4a[4][4];
      bool va = g < npairs;
      if (va) {
        int a = 0; while ((a + 1) * (a + 2) / 2 <= g) ++a;
        int b2 = g - a * (a + 1) / 2;
        IA = p + 1 + a; JA = p + 1 + b2;
#pragma unroll
        for (int ii = 0; ii < 4; ++ii) {
          float4 cv = *(const float4*)&Gb[(long)(16 * IA + 4 * ty + ii) * 256 + 16 * JA + 4 * tx];
          c4a[ii][0] = cv.x; c4a[ii][1] = cv.y; c4a[ii][2] = cv.z; c4a[ii][3] = cv.w;
        }
      }
      for (int pi0 = 0; pi0 < npairs; pi0 += 32) {
        // prefetch next pair's C block
        int IB = 0, JB = 0;
        float c4b[4][4];
        int piB = pi0 + 32 + g;
        bool vb = piB < npairs;
        if (vb) {
          int a = 0; while ((a + 1) * (a + 2) / 2 <= piB) ++a;
          int b2 = piB - a * (a + 1) / 2;
          IB = p + 1 + a; JB = p + 1 + b2;
#pragma unroll
          for (int ii = 0; ii < 4; ++ii) {
            float4 cv = *(const float4*)&Gb[(long)(16 * IB + 4 * ty + ii) * 256 + 16 * JB + 4 * tx];
            c4b[ii][0] = cv.x; c4b[ii][1] = cv.y; c4b[ii][2] = cv.z; c4b[ii][3] = cv.w;
          }
        }
        if (va) {
#pragma unroll
          for (int k4 = 0; k4 < 16; k4 += 4) {
            float4 a4[4], b4[4];
#pragma unroll
            for (int ii = 0; ii < 4; ++ii)
              a4[ii] = *(const float4*)&plds[(16 * IA + 4 * ty + ii) * 20 + k4];
#pragma unroll
            for (int jj = 0; jj < 4; ++jj)
              b4[jj] = *(const float4*)&plds[(16 * JA + 4 * tx + jj) * 20 + k4];
#pragma unroll
            for (int ii = 0; ii < 4; ++ii)
#pragma unroll
              for (int jj = 0; jj < 4; ++jj) {
                c4a[ii][jj] = fmaf(-a4[ii].x, b4[jj].x, c4a[ii][jj]);
                c4a[ii][jj] = fmaf(-a4[ii].y, b4[jj].y, c4a[ii][jj]);
                c4a[ii][jj] = fmaf(-a4[ii].z, b4[jj].z, c4a[ii][jj]);
                c4a[ii][jj] = fmaf(-a4[ii].w, b4[jj].w, c4a[ii][jj]);
              }
          }
          if (JA == p + 1) {
            // route to pa: next panel's A column (global copy is dead)
#pragma unroll
            for (int ii = 0; ii < 4; ++ii) {
              float4 cv = {c4a[ii][0], c4a[ii][1], c4a[ii][2], c4a[ii][3]};
              *(float4*)&pa[(16 * IA + 4 * ty + ii) * 20 + 4 * tx] = cv;
            }
          } else {
#pragma unroll
            for (int ii = 0; ii < 4; ++ii) {
              float4 cv = {c4a[ii][0], c4a[ii][1], c4a[ii][2], c4a[ii][3]};
              *(float4*)&Gb[(long)(16 * IA + 4 * ty + ii) * 256 + 16 * JA + 4 * tx] = cv;
            }
          }
        }
        // roll pipeline
        va = vb; IA = IB; JA = JB;
#pragma unroll
        for (int ii = 0; ii < 4; ++ii)
#pragma unroll
          for (int jj = 0; jj < 4; ++jj) c4a[ii][jj] = c4b[ii][jj];
      }
      __syncthreads();
    }
  } else if (bx < 64 + 2048) {
    // ---------- RFF(q) -> phiq bf16 hi/lo, 64 rows/block ----------
    const int id = bx - 64;
    const int l0 = (id & 31) * 64;
    const int h = (id >> 5) & 15;
    const int b = id >> 9;
    float* w_lds = sm;                // [64][132] = 8448
    float* x_lds = sm + 8448;         // [64][68]  = 4352
    float* b_lds = sm + 12800;        // [128]

    const float* wsrc = rffW + h * 8192;
    for (int f = tid * 4; f < 8192; f += 2048) {
      int d = f >> 7, m = f & 127;
      *(float4*)&w_lds[d * 132 + m] = *(const float4*)&wsrc[f];
    }
    if (tid < 128) b_lds[tid] = rffb[h * 128 + tid];
    {
      int r = tid >> 3, c0 = (tid & 7) * 8;
      const float* srow = qsrc + (long)(b * L_ + l0 + r) * 1024 + h * VD_ + c0;
      *(float4*)&x_lds[r * 68 + c0 + 0] = *(const float4*)(srow + 0);
      *(float4*)&x_lds[r * 68 + c0 + 4] = *(const float4*)(srow + 4);
    }
    __syncthreads();

    const int sub = tid >> 8;          // 0..1 -> row half
    const int t = tid & 255;
    const int ty = t >> 4, tx = t & 15;
    const int rrow = sub * 32 + 2 * ty;  // 2 rows per thread
    float acc[2][8];
    {
      float4 bb0 = *(const float4*)&b_lds[4 * tx];
      float4 bb1 = *(const float4*)&b_lds[4 * tx + 64];
#pragma unroll
      for (int i = 0; i < 2; ++i) {
        acc[i][0] = bb0.x; acc[i][1] = bb0.y; acc[i][2] = bb0.z; acc[i][3] = bb0.w;
        acc[i][4] = bb1.x; acc[i][5] = bb1.y; acc[i][6] = bb1.z; acc[i][7] = bb1.w;
      }
    }
#pragma unroll 8
    for (int kk = 0; kk < 64; ++kk) {
      float4 w0 = *(const float4*)&w_lds[kk * 132 + 4 * tx];
      float4 w1 = *(const float4*)&w_lds[kk * 132 + 4 * tx + 64];
      float xv[2];
#pragma unroll
      for (int i = 0; i < 2; ++i) xv[i] = x_lds[(rrow + i) * 68 + kk];
#pragma unroll
      for (int i = 0; i < 2; ++i) {
        acc[i][0] = fmaf(xv[i], w0.x, acc[i][0]);
        acc[i][1] = fmaf(xv[i], w0.y, acc[i][1]);
        acc[i][2] = fmaf(xv[i], w0.z, acc[i][2]);
        acc[i][3] = fmaf(xv[i], w0.w, acc[i][3]);
        acc[i][4] = fmaf(xv[i], w1.x, acc[i][4]);
        acc[i][5] = fmaf(xv[i], w1.y, acc[i][5]);
        acc[i][6] = fmaf(xv[i], w1.z, acc[i][6]);
        acc[i][7] = fmaf(xv[i], w1.w, acc[i][7]);
      }
    }
#pragma unroll
    for (int i = 0; i < 2; ++i) {
      int l = l0 + rrow + i;
      float4 c0, c1, s0, s1;
      float sv, cv;
      sincosf(acc[i][0], &sv, &cv); c0.x = cv * SCALE_; s0.x = sv * SCALE_;
      sincosf(acc[i][1], &sv, &cv); c0.y = cv * SCALE_; s0.y = sv * SCALE_;
      sincosf(acc[i][2], &sv, &cv); c0.z = cv * SCALE_; s0.z = sv * SCALE_;
      sincosf(acc[i][3], &sv, &cv); c0.w = cv * SCALE_; s0.w = sv * SCALE_;
      sincosf(acc[i][4], &sv, &cv); c1.x = cv * SCALE_; s1.x = sv * SCALE_;
      sincosf(acc[i][5], &sv, &cv); c1.y = cv * SCALE_; s1.y = sv * SCALE_;
      sincosf(acc[i][6], &sv, &cv); c1.z = cv * SCALE_; s1.z = sv * SCALE_;
      sincosf(acc[i][7], &sv, &cv); c1.w = cv * SCALE_; s1.w = sv * SCALE_;
      long base = ((long)(b * H_ + h) * L_ + l) * M2_;
      ushort4 hv; float4 r4;
      split4(c0, &hv, &r4);
      *(ushort4*)&ph[base + 4 * tx] = hv;
      *(ushort4*)&pl_out[base + 4 * tx] = (ushort4){f2bf(r4.x), f2bf(r4.y), f2bf(r4.z), f2bf(r4.w)};
      split4(c1, &hv, &r4);
      *(ushort4*)&ph[base + 64 + 4 * tx] = hv;
      *(ushort4*)&pl_out[base + 64 + 4 * tx] = (ushort4){f2bf(r4.x), f2bf(r4.y), f2bf(r4.z), f2bf(r4.w)};
      split4(s0, &hv, &r4);
      *(ushort4*)&ph[base + 128 + 4 * tx] = hv;
      *(ushort4*)&pl_out[base + 128 + 4 * tx] = (ushort4){f2bf(r4.x), f2bf(r4.y), f2bf(r4.z), f2bf(r4.w)};
      split4(s1, &hv, &r4);
      *(ushort4*)&ph[base + 192 + 4 * tx] = hv;
      *(ushort4*)&pl_out[base + 192 + 4 * tx] = (ushort4){f2bf(r4.x), f2bf(r4.y), f2bf(r4.z), f2bf(r4.w)};
    }
  } else {
    // ---------- Wo -> bf16 ----------
    const int id2 = bx - (64 + 2048);
    int idx = id2 * 512 + tid;
    for (int i = idx; i < 262144; i += 65536) {
      float4 f = ((const float4*)Wo)[i];
      ushort4 hv = {f2bf(f.x), f2bf(f.y), f2bf(f.z), f2bf(f.w)};
      ((ushort4*)wo_hi)[i] = hv;
    }
  }
}

// ---------------- blocked triangular solves (dense L/invD in G) -------------
// XCD-swizzled so the 4 d0-slices of one bh co-reside on one XCD's L2
// (each re-reads the same 256KB L panel).
__global__ __launch_bounds__(256) void tri_solve_kernel(
    const float* __restrict__ Gw, const float* __restrict__ T,
    u16* __restrict__ wth, u16* __restrict__ wtl)
{
  __shared__ float Y[256 * 17];
  __shared__ float tmp[16 * 17];
  int bxx = blockIdx.x, byy = blockIdx.y;
  swz2d(&bxx, &byy);
  const int bh = byy;
  const int d0 = bxx * 16;
  const int tid = threadIdx.x;
  const int i = tid >> 4, d = tid & 15;
  const float* Gb = Gw + (long)bh * 65536;
  const float* Tb = T + (long)bh * 16384;

  for (int r = i; r < 256; r += 16) Y[r * 17 + d] = Tb[r * 64 + d0 + d];
  __syncthreads();

  for (int J = 0; J < 16; ++J) {
    float acc = Y[(J * 16 + i) * 17 + d];
    for (int c = 0; c < J; ++c) {
      const float* Lblk = &Gb[(long)(16 * J + i) * 256 + 16 * c];
#pragma unroll
      for (int k = 0; k < 16; k += 4) {
        float4 l4 = *(const float4*)&Lblk[k];
        acc = fmaf(-l4.x, Y[(c * 16 + k + 0) * 17 + d], acc);
        acc = fmaf(-l4.y, Y[(c * 16 + k + 1) * 17 + d], acc);
        acc = fmaf(-l4.z, Y[(c * 16 + k + 2) * 17 + d], acc);
        acc = fmaf(-l4.w, Y[(c * 16 + k + 3) * 17 + d], acc);
      }
    }
    tmp[i * 17 + d] = acc;
    __syncthreads();
    const float* invD = &Gb[(long)(16 * J + i) * 256 + 16 * J];
    float y = 0.f;
#pragma unroll
    for (int k = 0; k < 16; ++k) y = fmaf(invD[k], tmp[k * 17 + d], y);
    Y[(J * 16 + i) * 17 + d] = y;
    __syncthreads();
  }

  for (int J = 15; J >= 0; --J) {
    float acc = Y[(J * 16 + i) * 17 + d];
    for (int I = J + 1; I < 16; ++I) {
#pragma unroll
      for (int k = 0; k < 16; ++k)
        acc = fmaf(-Gb[(long)(16 * I + k) * 256 + 16 * J + i], Y[(I * 16 + k) * 17 + d], acc);
    }
    tmp[i * 17 + d] = acc;
    __syncthreads();
    float w = 0.f;
#pragma unroll
    for (int k = 0; k < 16; ++k)
      w = fmaf(Gb[(long)(16 * J + k) * 256 + 16 * J + i], tmp[k * 17 + d], w);
    Y[(J * 16 + i) * 17 + d] = w;
    __syncthreads();
  }

  for (int f = tid; f < 16 * 256; f += 256) {
    int dc = f >> 8, m = f & 255;
    float val = Y[m * 17 + dc];
    u16 h = f2bf(val);
    long o = (long)bh * 16384 + (long)(d0 + dc) * 256 + m;
    wth[o] = h;
    wtl[o] = f2bf(val - bf2f(h));
  }
}

__global__ void ws_too_small_kernel(float* out) { out[0] = 12345.0f; }

extern "C" void kernel_launch(void* const* d_in, const int* in_sizes, int n_in,
                              void* d_out, int out_size, void* d_ws, size_t ws_size,
                              hipStream_t stream) {
  const float* x    = (const float*)d_in[0];
  const float* mask = (const float*)d_in[2];
  const float* Wq   = (const float*)d_in[3];
  const float* Wk   = (const float*)d_in[4];
  const float* Wv   = (const float*)d_in[5];
  const float* Wo   = (const float*)d_in[6];
  const float* bo   = (const float*)d_in[7];
  const float* rffW = (const float*)d_in[8];
  const float* rffb = (const float*)d_in[9];
  float* out = (float*)d_out;
  float* ws  = (float*)d_ws;

  const size_t needed = 58720256UL * 4UL;  // 234.9 MB
  if (ws_size < needed) {
    ws_too_small_kernel<<<1, 1, 0, stream>>>(out);
    return;
  }
  // region A [0, 8.4M): q fp32 -> oh bf16 after rff(q)
  float* q = ws;
  u16* oh_bf = (u16*)ws;
  // region B [8.4M, 16.7M): k fp32 -> T(1M)+G(4.2M) after reduce (kbuf dead)
  float* kbuf = ws + 8388608;
  float* T    = ws + 8388608;
  float* G    = ws + 9437184;
  // region big [16.7M, 50.3M):
  u16* big16 = (u16*)(ws + 16777216);
  u16* x_hi = big16;
  u16* x_lo = big16 + 8388608;
  u16* w_hi = big16 + 16777216;
  u16* w_lo = big16 + 19922944;
  u16* pk_hi = big16;                      // [0, 20971520) u16
  u16* pk_lo = big16 + 20971520;           // [20971520, 41943040) u16
  float* Gp = ws + 37748736;               // 2 x 4194304 floats
  float* Tp = ws + 46137344;               // 2 x 1048576 floats
  u16* phiq_hi = big16;                    // after reduce, whole big region
  u16* phiq_lo = big16 + 33554432;         // (overlaps Gp/Tp -> reduce first!)
  // region D [50.3M, 58.7M): v fp32 -> wt/wo bf16
  float* v = ws + 50331648;
  u16* wt_hi = (u16*)(ws + 50331648);
  u16* wt_lo = wt_hi + 1048576;
  u16* wo_hi = wt_hi + 2097152;

  hipFuncSetAttribute((const void*)chol_rffq_wo_kernel,
                      hipFuncAttributeMaxDynamicSharedMemorySize, 51712);

  dim3 blk(256);

  // 1: convert x and W to bf16 hi/lo
  cvt_split_kernel<<<8192, blk, 0, stream>>>(x, x_hi, x_lo, 2097152);
  cvt_split_kernel<<<1024, blk, 0, stream>>>(Wq, w_hi,           w_lo,           262144);
  cvt_split_kernel<<<1024, blk, 0, stream>>>(Wk, w_hi + 1048576, w_lo + 1048576, 262144);
  cvt_split_kernel<<<1024, blk, 0, stream>>>(Wv, w_hi + 2097152, w_lo + 2097152, 262144);

  // 2: QKV — qk 3-pass (uniform) + v hi-only (separate: fusion regressed 2x)
  mfma_qk3<<<dim3(16, 64), blk, 0, stream>>>(x_hi, x_lo, w_hi, w_lo, q, kbuf);
  mfma_nt<<<dim3(8, 64), blk, 0, stream>>>(x_hi, w_hi + 2097152, v,
                                           1024, 1024, 1024, 1024, nullptr, nullptr);

  // 3: two bh-halves: rff(k)->pkT, vT->pkT, [G-lower|T] MFMA (K-split x2)
  for (int half = 0; half < 2; ++half) {
    int b0 = half * 2, bh0 = half * 32;
    rff_k_t<<<dim3(32, 16, 2), blk, 0, stream>>>(kbuf, mask, rffW, rffb, pk_hi, pk_lo, b0);
    vt_kernel<<<dim3(16, 32), blk, 0, stream>>>(v, mask, pk_hi, pk_lo, b0);
    mfma_gt<<<dim3(8, 2, 32), blk, 0, stream>>>(pk_hi, pk_lo, Gp, Tp, bh0);
  }

  // 4: reduce partials -> final G, T (MUST precede phiq write: aliasing)
  reduce_gt_kernel<<<5120, blk, 0, stream>>>(Gp, G, Tp, T);

  // 5: fused out-of-core chol (in-place on G) + rff(q)->phiq + Wo cvt
  chol_rffq_wo_kernel<<<dim3(64 + 2048 + 128), dim3(512), 51712, stream>>>(
      G, q, rffW, rffb, phiq_hi, phiq_lo, Wo, wo_hi);

  // 6: tri solves (dense L/invD from G) -> wt bf16 hi/lo
  tri_solve_kernel<<<dim3(4, 64), dim3(256), 0, stream>>>(G, T, wt_hi, wt_lo);

  // 7: out-heads MFMA (bf16 output)
  mfma_out_k<<<dim3(16, 64), blk, 0, stream>>>(phiq_hi, phiq_lo, wt_hi, wt_lo, oh_bf);

  // 8: Wo projection (bf16 MFMA) with bias+mask epilogue
  mfma_nt<<<dim3(8, 64), blk, 0, stream>>>(oh_bf, wo_hi, out, 1024, 1024, 1024, 1024, bo, mask);
}

// Round 10
// 778.704 us; speedup vs baseline: 1.0362x; 1.0362x over previous
//
#include <hip/hip_runtime.h>
#include <math.h>

#define B_ 4
#define L_ 2048
#define HD_ 1024
#define H_ 16
#define VD_ 64
#define M_ 128
#define M2_ 256
#define RIDGE_ 0.01f
#define SCALE_ 0.08838834764831845f   // 1/sqrt(128)

typedef unsigned short u16;
typedef __attribute__((ext_vector_type(8))) short short8;
typedef __attribute__((ext_vector_type(4))) float floatx4;

__device__ __forceinline__ u16 f2bf(float x) {
  unsigned u = __float_as_uint(x);
  unsigned r = u + 0x7fff + ((u >> 16) & 1);
  return (u16)(r >> 16);
}
__device__ __forceinline__ float bf2f(u16 h) {
  return __uint_as_float(((unsigned)h) << 16);
}
__device__ __forceinline__ void gload_lds16(const u16* g, u16* l) {
  __builtin_amdgcn_global_load_lds(
      (const __attribute__((address_space(1))) unsigned int*)g,
      (__attribute__((address_space(3))) unsigned int*)l, 16, 0, 0);
}
__device__ __forceinline__ void split4(float4 f, ushort4* h, float4* r) {
  h->x = f2bf(f.x); h->y = f2bf(f.y); h->z = f2bf(f.z); h->w = f2bf(f.w);
  r->x = f.x - bf2f(h->x); r->y = f.y - bf2f(h->y);
  r->z = f.z - bf2f(h->z); r->w = f.w - bf2f(h->w);
}
// counted vmcnt (never 0 in loop) + raw barrier with compiler fences:
// loads for the NEXT tile stay in flight across the barrier (T3/T4).
#define WAITVM(N) asm volatile("s_waitcnt vmcnt(" #N ")" ::: "memory")
__device__ __forceinline__ void barf() {
  asm volatile("" ::: "memory");
  __builtin_amdgcn_s_barrier();
  asm volatile("" ::: "memory");
}
// bijective XCD swizzle: consecutive remapped ids (same XCD) walk x within a
// y-row, so blocks sharing an A-panel co-reside on one XCD's L2. nwg%8==0.
__device__ __forceinline__ void swz2d(int* bx, int* by) {
  int gx = gridDim.x;
  int nwg = gx * gridDim.y;
  int orig = (*by) * gx + (*bx);
  int wg = (orig & 7) * (nwg >> 3) + (orig >> 3);
  *bx = wg % gx;
  *by = wg / gx;
}

// ---------------- fp32 -> bf16 hi/lo split ---------------------------------
__global__ __launch_bounds__(256) void cvt_split_kernel(
    const float* __restrict__ src, u16* __restrict__ hi, u16* __restrict__ lo, int n4)
{
  int i = blockIdx.x * 256 + threadIdx.x;
  if (i < n4) {
    float4 f = ((const float4*)src)[i];
    ushort4 hv; float4 r;
    split4(f, &hv, &r);
    ushort4 lv = {f2bf(r.x), f2bf(r.y), f2bf(r.z), f2bf(r.w)};
    ((ushort4*)hi)[i] = hv;
    ((ushort4*)lo)[i] = lv;
  }
}

// ---------------- bf16 MFMA GEMM (counted-vmcnt pipeline), C = A * B^T -----
__global__ __launch_bounds__(256) void mfma_nt(
    const u16* __restrict__ A0, const u16* __restrict__ B0,
    float* __restrict__ C, int Ndim, int Kdim, int ldA, int ldB,
    const float* __restrict__ bias, const float* __restrict__ mask)
{
  __shared__ __align__(16) u16 a_sm[2][4096];
  __shared__ __align__(16) u16 b_sm[2][4096];
  const int tid = threadIdx.x;
  const int wave = tid >> 6, lane = tid & 63;
  int bx = blockIdx.x, by = blockIdx.y;
  swz2d(&bx, &by);
  const int m0 = by * 128, n0 = bx * 128;
  const int wrow = (wave >> 1) * 64, wcol = (wave & 1) * 64;
  const int fm = lane & 15, q = lane >> 4;
  const int lofs = wave * 1024;

  floatx4 acc[4][4];
#pragma unroll
  for (int i = 0; i < 4; ++i)
#pragma unroll
    for (int j = 0; j < 4; ++j) acc[i][j] = (floatx4){0.f, 0.f, 0.f, 0.f};

  const u16* Ag0 = A0 + (long)(m0 + lane) * ldA + wave * 8;
  const u16* Ag1 = A0 + (long)(m0 + 64 + lane) * ldA + wave * 8;
  const u16* Bg0 = B0 + (long)(n0 + lane) * ldB + wave * 8;
  const u16* Bg1 = B0 + (long)(n0 + 64 + lane) * ldB + wave * 8;

  auto stage = [&](int d, int k0) {
    gload_lds16(Ag0 + k0, &a_sm[d][lofs]);
    gload_lds16(Ag1 + k0, &a_sm[d][lofs + 512]);
    gload_lds16(Bg0 + k0, &b_sm[d][lofs]);
    gload_lds16(Bg1 + k0, &b_sm[d][lofs + 512]);
  };
  auto compute = [&](int d) {
    short8 af[4], bfv[4];
#pragma unroll
    for (int i = 0; i < 4; ++i)
      af[i] = *(const short8*)&a_sm[d][(q * 128 + wrow + i * 16 + fm) * 8];
#pragma unroll
    for (int j = 0; j < 4; ++j)
      bfv[j] = *(const short8*)&b_sm[d][(q * 128 + wcol + j * 16 + fm) * 8];
    __builtin_amdgcn_s_setprio(1);
#pragma unroll
    for (int i = 0; i < 4; ++i)
#pragma unroll
      for (int j = 0; j < 4; ++j)
        acc[i][j] = __builtin_amdgcn_mfma_f32_16x16x32_bf16(af[i], bfv[j], acc[i][j], 0, 0, 0);
    __builtin_amdgcn_s_setprio(0);
  };

  stage(0, 0);
  stage(1, 32);
  for (int k = 0; k + 64 < Kdim; k += 64) {
    WAITVM(4); barf();
    compute(0);
    barf();
    stage(0, k + 64);
    WAITVM(4); barf();
    compute(1);
    barf();
    stage(1, k + 96);
  }
  WAITVM(4); barf();
  compute(0);
  barf();
  WAITVM(0); barf();
  compute(1);

  const int colb = n0 + wcol + fm;
  const int rbase = m0 + wrow + (lane >> 4) * 4;
#pragma unroll
  for (int j = 0; j < 4; ++j) {
    int cg = colb + j * 16;
    float bb = bias ? bias[cg] : 0.f;
#pragma unroll
    for (int i = 0; i < 4; ++i) {
#pragma unroll
      for (int r = 0; r < 4; ++r) {
        int row = rbase + i * 16 + r;
        float val = acc[i][j][r];
        if (bias) val = (val + bb) * mask[row];
        C[(long)row * Ndim + cg] = val;
      }
    }
  }
}

// ---------------- uniform bf16x3 MFMA GEMM (q,k columns only) ---------------
__global__ __launch_bounds__(256) void mfma_qk3(
    const u16* __restrict__ Ah, const u16* __restrict__ Al,
    const u16* __restrict__ Bh, const u16* __restrict__ Bl,
    float* __restrict__ Cq, float* __restrict__ Ck)
{
  __shared__ __align__(16) u16 ah_sm[2][4096], al_sm[2][4096];
  __shared__ __align__(16) u16 bh_sm[2][4096], bl_sm[2][4096];
  const int tid = threadIdx.x;
  const int wave = tid >> 6, lane = tid & 63;
  int bx = blockIdx.x, by = blockIdx.y;
  swz2d(&bx, &by);
  const int m0 = by * 128, n0 = bx * 128;
  const int wrow = (wave >> 1) * 64, wcol = (wave & 1) * 64;
  const int fm = lane & 15, q = lane >> 4;
  const int lofs = wave * 1024;

  floatx4 acc[4][4];
#pragma unroll
  for (int i = 0; i < 4; ++i)
#pragma unroll
    for (int j = 0; j < 4; ++j) acc[i][j] = (floatx4){0.f, 0.f, 0.f, 0.f};

  const long a0o = (long)(m0 + lane) * 1024 + wave * 8;
  const long a1o = (long)(m0 + 64 + lane) * 1024 + wave * 8;
  const long b0o = (long)(n0 + lane) * 1024 + wave * 8;
  const long b1o = (long)(n0 + 64 + lane) * 1024 + wave * 8;

  auto stage = [&](int d, int k0) {
    gload_lds16(Ah + a0o + k0, &ah_sm[d][lofs]);
    gload_lds16(Ah + a1o + k0, &ah_sm[d][lofs + 512]);
    gload_lds16(Al + a0o + k0, &al_sm[d][lofs]);
    gload_lds16(Al + a1o + k0, &al_sm[d][lofs + 512]);
    gload_lds16(Bh + b0o + k0, &bh_sm[d][lofs]);
    gload_lds16(Bh + b1o + k0, &bh_sm[d][lofs + 512]);
    gload_lds16(Bl + b0o + k0, &bl_sm[d][lofs]);
    gload_lds16(Bl + b1o + k0, &bl_sm[d][lofs + 512]);
  };
  auto compute = [&](int d) {
    short8 afh[4], afl[4], bfh[4], bfl[4];
#pragma unroll
    for (int i = 0; i < 4; ++i) {
      afh[i] = *(const short8*)&ah_sm[d][(q * 128 + wrow + i * 16 + fm) * 8];
      afl[i] = *(const short8*)&al_sm[d][(q * 128 + wrow + i * 16 + fm) * 8];
    }
#pragma unroll
    for (int j = 0; j < 4; ++j) {
      bfh[j] = *(const short8*)&bh_sm[d][(q * 128 + wcol + j * 16 + fm) * 8];
      bfl[j] = *(const short8*)&bl_sm[d][(q * 128 + wcol + j * 16 + fm) * 8];
    }
    __builtin_amdgcn_s_setprio(1);
#pragma unroll
    for (int i = 0; i < 4; ++i)
#pragma unroll
      for (int j = 0; j < 4; ++j) {
        acc[i][j] = __builtin_amdgcn_mfma_f32_16x16x32_bf16(afh[i], bfh[j], acc[i][j], 0, 0, 0);
        acc[i][j] = __builtin_amdgcn_mfma_f32_16x16x32_bf16(afl[i], bfh[j], acc[i][j], 0, 0, 0);
        acc[i][j] = __builtin_amdgcn_mfma_f32_16x16x32_bf16(afh[i], bfl[j], acc[i][j], 0, 0, 0);
      }
    __builtin_amdgcn_s_setprio(0);
  };

  stage(0, 0);
  stage(1, 32);
  for (int k = 0; k + 64 < 1024; k += 64) {
    WAITVM(8); barf();
    compute(0);
    barf();
    stage(0, k + 64);
    WAITVM(8); barf();
    compute(1);
    barf();
    stage(1, k + 96);
  }
  WAITVM(8); barf();
  compute(0);
  barf();
  WAITVM(0); barf();
  compute(1);

  float* Cp; int cb;
  if (n0 < 1024) { Cp = Cq; cb = n0; }
  else           { Cp = Ck; cb = n0 - 1024; }
  const int colb = cb + wcol + fm;
  const int rbase = m0 + wrow + (lane >> 4) * 4;
#pragma unroll
  for (int j = 0; j < 4; ++j) {
    int cg = colb + j * 16;
#pragma unroll
    for (int i = 0; i < 4; ++i)
#pragma unroll
      for (int r = 0; r < 4; ++r)
        Cp[(long)(rbase + i * 16 + r) * 1024 + cg] = acc[i][j][r];
  }
}

// ---------------- RFF(k): transposed bf16 hi/lo into pkT --------------------
__global__ __launch_bounds__(256) void rff_k_t(
    const float* __restrict__ src, const float* __restrict__ mask,
    const float* __restrict__ rffW, const float* __restrict__ rffb,
    u16* __restrict__ pkh, u16* __restrict__ pkl, int b0)
{
  __shared__ __align__(16) float w_lds[64][132];
  __shared__ __align__(16) float x_lds[64][68];
  __shared__ float b_lds[128];
  const int l0 = blockIdx.x * 64;
  const int h = blockIdx.y, b = b0 + blockIdx.z;
  const int zloc = blockIdx.z * 16 + h;
  const int tid = threadIdx.x;

  const float* wsrc = rffW + h * 8192;
  for (int f = tid * 4; f < 8192; f += 1024) {
    int d = f >> 7, m = f & 127;
    *(float4*)&w_lds[d][m] = *(const float4*)&wsrc[f];
  }
  if (tid < 128) b_lds[tid] = rffb[h * 128 + tid];
  {
    int r = tid >> 2, c0 = (tid & 3) * 16;
    const float* srow = src + (long)(b * L_ + l0 + r) * 1024 + h * VD_ + c0;
    *(float4*)&x_lds[r][c0 + 0]  = *(const float4*)(srow + 0);
    *(float4*)&x_lds[r][c0 + 4]  = *(const float4*)(srow + 4);
    *(float4*)&x_lds[r][c0 + 8]  = *(const float4*)(srow + 8);
    *(float4*)&x_lds[r][c0 + 12] = *(const float4*)(srow + 12);
  }
  __syncthreads();

  const int ty = tid >> 4, tx = tid & 15;
  float acc[4][8];
  {
    float4 bb0 = *(const float4*)&b_lds[4 * tx];
    float4 bb1 = *(const float4*)&b_lds[4 * tx + 64];
#pragma unroll
    for (int i = 0; i < 4; ++i) {
      acc[i][0] = bb0.x; acc[i][1] = bb0.y; acc[i][2] = bb0.z; acc[i][3] = bb0.w;
      acc[i][4] = bb1.x; acc[i][5] = bb1.y; acc[i][6] = bb1.z; acc[i][7] = bb1.w;
    }
  }
#pragma unroll 8
  for (int kk = 0; kk < 64; ++kk) {
    float4 w0 = *(const float4*)&w_lds[kk][4 * tx];
    float4 w1 = *(const float4*)&w_lds[kk][4 * tx + 64];
    float xv[4];
#pragma unroll
    for (int i = 0; i < 4; ++i) xv[i] = x_lds[4 * ty + i][kk];
#pragma unroll
    for (int i = 0; i < 4; ++i) {
      acc[i][0] = fmaf(xv[i], w0.x, acc[i][0]);
      acc[i][1] = fmaf(xv[i], w0.y, acc[i][1]);
      acc[i][2] = fmaf(xv[i], w0.z, acc[i][2]);
      acc[i][3] = fmaf(xv[i], w0.w, acc[i][3]);
      acc[i][4] = fmaf(xv[i], w1.x, acc[i][4]);
      acc[i][5] = fmaf(xv[i], w1.y, acc[i][5]);
      acc[i][6] = fmaf(xv[i], w1.z, acc[i][6]);
      acc[i][7] = fmaf(xv[i], w1.w, acc[i][7]);
    }
  }
  float fi[4];
#pragma unroll
  for (int i = 0; i < 4; ++i) fi[i] = SCALE_ * mask[b * L_ + l0 + 4 * ty + i];
  float cvv[4][8], svv[4][8];
#pragma unroll
  for (int i = 0; i < 4; ++i)
#pragma unroll
    for (int jj = 0; jj < 8; ++jj) {
      float sv, cv;
      sincosf(acc[i][jj], &sv, &cv);
      cvv[i][jj] = cv * fi[i];
      svv[i][jj] = sv * fi[i];
    }
  const long lbase = l0 + 4 * ty;
  const long zbase = (long)zloc * 655360;
#pragma unroll
  for (int jj = 0; jj < 8; ++jj) {
    int mcol = (jj < 4) ? (4 * tx + jj) : (64 + 4 * tx + (jj - 4));
    ushort4 h4, l4;
    h4.x = f2bf(cvv[0][jj]); l4.x = f2bf(cvv[0][jj] - bf2f(h4.x));
    h4.y = f2bf(cvv[1][jj]); l4.y = f2bf(cvv[1][jj] - bf2f(h4.y));
    h4.z = f2bf(cvv[2][jj]); l4.z = f2bf(cvv[2][jj] - bf2f(h4.z));
    h4.w = f2bf(cvv[3][jj]); l4.w = f2bf(cvv[3][jj] - bf2f(h4.w));
    long base = zbase + (long)mcol * 2048 + lbase;
    *(ushort4*)&pkh[base] = h4;
    *(ushort4*)&pkl[base] = l4;
    ushort4 hs, ls;
    hs.x = f2bf(svv[0][jj]); ls.x = f2bf(svv[0][jj] - bf2f(hs.x));
    hs.y = f2bf(svv[1][jj]); ls.y = f2bf(svv[1][jj] - bf2f(hs.y));
    hs.z = f2bf(svv[2][jj]); ls.z = f2bf(svv[2][jj] - bf2f(hs.z));
    hs.w = f2bf(svv[3][jj]); ls.w = f2bf(svv[3][jj] - bf2f(hs.w));
    long base2 = zbase + (long)(mcol + 128) * 2048 + lbase;
    *(ushort4*)&pkh[base2] = hs;
    *(ushort4*)&pkl[base2] = ls;
  }
}

// ---------------- masked V transpose into pkT rows 256..319 -----------------
__global__ __launch_bounds__(256) void vt_kernel(
    const float* __restrict__ v, const float* __restrict__ mask,
    u16* __restrict__ pkh, u16* __restrict__ pkl, int b0)
{
  __shared__ float t[128][65];
  const int z = blockIdx.y;
  const int b = b0 + (z >> 4), h = z & 15;
  const int l0 = blockIdx.x * 128;
  const int tid = threadIdx.x;
  const int d = tid & 63, lg = tid >> 6;
  for (int i = 0; i < 128; i += 4) {
    int ll = i + lg;
    float mv = mask[b * L_ + l0 + ll];
    t[ll][d] = v[(long)(b * L_ + l0 + ll) * 1024 + h * 64 + d] * mv;
  }
  __syncthreads();
  const int d2 = tid >> 2, lofs = (tid & 3) * 32;
  long base = (long)z * 655360 + (long)(256 + d2) * 2048 + l0 + lofs;
  for (int j = 0; j < 32; j += 4) {
    float f0 = t[lofs + j + 0][d2], f1 = t[lofs + j + 1][d2];
    float f2 = t[lofs + j + 2][d2], f3 = t[lofs + j + 3][d2];
    ushort4 hv, lv;
    hv.x = f2bf(f0); lv.x = f2bf(f0 - bf2f(hv.x));
    hv.y = f2bf(f1); lv.y = f2bf(f1 - bf2f(hv.y));
    hv.z = f2bf(f2); lv.z = f2bf(f2 - bf2f(hv.z));
    hv.w = f2bf(f3); lv.w = f2bf(f3 - bf2f(hv.w));
    *(ushort4*)&pkh[base + j] = hv;
    *(ushort4*)&pkl[base + j] = lv;
  }
}

// ---------------- batched bf16x3 MFMA: [G-lower|T] partials, K-split x2 -----
// G is symmetric and only its lower triangle + diag are consumed downstream
// (chol reads row>=col; tri_solve fwd reads L lower, bwd reads transposed
// lower; invD diag). Skip the 2 strictly-upper 128x64 blocks per (kc,z).
__global__ __launch_bounds__(256) void mfma_gt(
    const u16* __restrict__ pkh, const u16* __restrict__ pkl,
    float* __restrict__ Gp, float* __restrict__ Tp, int bh0)
{
  __shared__ __align__(16) u16 ah_sm[2][4096], al_sm[2][4096];
  __shared__ __align__(16) u16 bh_sm[2][2048], bl_sm[2][2048];
  const int tid = threadIdx.x;
  const int wave = tid >> 6, lane = tid & 63;
  // grid = (8 combos, 2 kc, 32 z); bijective XCD swizzle over 512 wgs
  int orig = (blockIdx.z * gridDim.y + blockIdx.y) * gridDim.x + blockIdx.x;
  int wg = (orig & 7) * 64 + (orig >> 3);
  const int cx = wg & 7;
  const int rr = wg >> 3;
  const int kc = rr & 1;
  const int z = rr >> 1;
  int mt, n0;
  if (cx < 3) { mt = 0; n0 = (cx == 2) ? 256 : cx * 64; }
  else        { mt = 1; n0 = (cx - 3) * 64; }
  const int m0 = mt * 128;
  const int wrow = (wave >> 1) * 64, wcol = (wave & 1) * 32;
  const int fm = lane & 15, q = lane >> 4;
  const long batch = (long)z * 655360;
  const u16* Ahp = pkh + batch;
  const u16* Alp = pkl + batch;
  const int lofsA = wave * 1024;
  const int lofsB = wave * 512;

  floatx4 acc[4][2];
#pragma unroll
  for (int i = 0; i < 4; ++i)
#pragma unroll
    for (int j = 0; j < 2; ++j) acc[i][j] = (floatx4){0.f, 0.f, 0.f, 0.f};

  const long a0o = (long)(m0 + lane) * 2048 + wave * 8;
  const long a1o = (long)(m0 + 64 + lane) * 2048 + wave * 8;
  const long b0o = (long)(n0 + lane) * 2048 + wave * 8;

  auto stage = [&](int d, int k0) {
    gload_lds16(Ahp + a0o + k0, &ah_sm[d][lofsA]);
    gload_lds16(Ahp + a1o + k0, &ah_sm[d][lofsA + 512]);
    gload_lds16(Alp + a0o + k0, &al_sm[d][lofsA]);
    gload_lds16(Alp + a1o + k0, &al_sm[d][lofsA + 512]);
    gload_lds16(Ahp + b0o + k0, &bh_sm[d][lofsB]);
    gload_lds16(Alp + b0o + k0, &bl_sm[d][lofsB]);
  };
  auto compute = [&](int d) {
    short8 afh[4], afl[4], bfh[2], bfl[2];
#pragma unroll
    for (int i = 0; i < 4; ++i) {
      afh[i] = *(const short8*)&ah_sm[d][(q * 128 + wrow + i * 16 + fm) * 8];
      afl[i] = *(const short8*)&al_sm[d][(q * 128 + wrow + i * 16 + fm) * 8];
    }
#pragma unroll
    for (int j = 0; j < 2; ++j) {
      bfh[j] = *(const short8*)&bh_sm[d][(q * 64 + wcol + j * 16 + fm) * 8];
      bfl[j] = *(const short8*)&bl_sm[d][(q * 64 + wcol + j * 16 + fm) * 8];
    }
    __builtin_amdgcn_s_setprio(1);
#pragma unroll
    for (int i = 0; i < 4; ++i)
#pragma unroll
      for (int j = 0; j < 2; ++j) {
        acc[i][j] = __builtin_amdgcn_mfma_f32_16x16x32_bf16(afh[i], bfh[j], acc[i][j], 0, 0, 0);
        acc[i][j] = __builtin_amdgcn_mfma_f32_16x16x32_bf16(afl[i], bfh[j], acc[i][j], 0, 0, 0);
        acc[i][j] = __builtin_amdgcn_mfma_f32_16x16x32_bf16(afh[i], bfl[j], acc[i][j], 0, 0, 0);
      }
    __builtin_amdgcn_s_setprio(0);
  };

  const int kbeg = kc * 1024, kend = kbeg + 1024;
  stage(0, kbeg);
  stage(1, kbeg + 32);
  for (int k = kbeg; k + 64 < kend; k += 64) {
    WAITVM(6); barf();
    compute(0);
    barf();
    stage(0, k + 64);
    WAITVM(6); barf();
    compute(1);
    barf();
    stage(1, k + 96);
  }
  WAITVM(6); barf();
  compute(0);
  barf();
  WAITVM(0); barf();
  compute(1);

  const int bh = bh0 + z;
  float* Gb = Gp + (long)kc * 4194304;
  float* Tb = Tp + (long)kc * 1048576;
  const int rbase = m0 + wrow + (lane >> 4) * 4;
#pragma unroll
  for (int j = 0; j < 2; ++j) {
    int col = n0 + wcol + j * 16 + fm;
#pragma unroll
    for (int i = 0; i < 4; ++i)
#pragma unroll
      for (int r = 0; r < 4; ++r) {
        int row = rbase + i * 16 + r;
        float val = acc[i][j][r];
        if (n0 < 256) Gb[(long)bh * 65536 + (long)row * 256 + col] = val;
        else Tb[(long)bh * 16384 + (long)row * 64 + (col - 256)] = val;
      }
  }
}

// ---------------- reduce K-split partials into final G, T -------------------
// (T must be reduced BEFORE chol_rffq writes phiq: Tp aliases phiq_lo.)
__global__ __launch_bounds__(256) void reduce_gt_kernel(
    const float* __restrict__ Gp, float* __restrict__ G,
    const float* __restrict__ Tp, float* __restrict__ T)
{
  long i = (long)blockIdx.x * 256 + threadIdx.x;  // float4 index
  if (i < 1048576) {
    float4 a = ((const float4*)Gp)[i];
    float4 b = ((const float4*)(Gp + 4194304))[i];
    float4 o = {a.x + b.x, a.y + b.y, a.z + b.z, a.w + b.w};
    ((float4*)G)[i] = o;
  } else {
    long j = i - 1048576;
    float4 a = ((const float4*)Tp)[j];
    float4 b = ((const float4*)(Tp + 1048576))[j];
    float4 o = {a.x + b.x, a.y + b.y, a.z + b.z, a.w + b.w};
    ((float4*)T)[j] = o;
  }
}

// ---------------- batched bf16x3 MFMA: oh = PhiQ @ Wt^T (bf16 out) ----------
__global__ __launch_bounds__(256) void mfma_out_k(
    const u16* __restrict__ ph, const u16* __restrict__ pl,
    const u16* __restrict__ wth, const u16* __restrict__ wtl,
    u16* __restrict__ oh)
{
  __shared__ __align__(16) u16 ah_sm[2][4096], al_sm[2][4096];
  __shared__ __align__(16) u16 bh_sm[2][2048], bl_sm[2][2048];
  const int tid = threadIdx.x;
  const int wave = tid >> 6, lane = tid & 63;
  int bx = blockIdx.x, by = blockIdx.y;
  swz2d(&bx, &by);
  const int bh = by;
  const int b = bh >> 4, h = bh & 15;
  const int l0 = bx * 128;
  const int wrow = (wave >> 1) * 64, wcol = (wave & 1) * 32;
  const int fm = lane & 15, q = lane >> 4;
  const u16* Ahp = ph + (long)bh * 524288 + (long)l0 * 256;
  const u16* Alp = pl + (long)bh * 524288 + (long)l0 * 256;
  const u16* Bhp = wth + (long)bh * 16384;
  const u16* Blp = wtl + (long)bh * 16384;
  const int lofsA = wave * 1024;
  const int lofsB = wave * 512;

  floatx4 acc[4][2];
#pragma unroll
  for (int i = 0; i < 4; ++i)
#pragma unroll
    for (int j = 0; j < 2; ++j) acc[i][j] = (floatx4){0.f, 0.f, 0.f, 0.f};

  const long a0o = (long)lane * 256 + wave * 8;
  const long a1o = (long)(64 + lane) * 256 + wave * 8;
  const long b0o = (long)lane * 256 + wave * 8;

  auto stage = [&](int d, int k0) {
    gload_lds16(Ahp + a0o + k0, &ah_sm[d][lofsA]);
    gload_lds16(Ahp + a1o + k0, &ah_sm[d][lofsA + 512]);
    gload_lds16(Alp + a0o + k0, &al_sm[d][lofsA]);
    gload_lds16(Alp + a1o + k0, &al_sm[d][lofsA + 512]);
    gload_lds16(Bhp + b0o + k0, &bh_sm[d][lofsB]);
    gload_lds16(Blp + b0o + k0, &bl_sm[d][lofsB]);
  };
  auto compute = [&](int d) {
    short8 afh[4], afl[4], bfh[2], bfl[2];
#pragma unroll
    for (int i = 0; i < 4; ++i) {
      afh[i] = *(const short8*)&ah_sm[d][(q * 128 + wrow + i * 16 + fm) * 8];
      afl[i] = *(const short8*)&al_sm[d][(q * 128 + wrow + i * 16 + fm) * 8];
    }
#pragma unroll
    for (int j = 0; j < 2; ++j) {
      bfh[j] = *(const short8*)&bh_sm[d][(q * 64 + wcol + j * 16 + fm) * 8];
      bfl[j] = *(const short8*)&bl_sm[d][(q * 64 + wcol + j * 16 + fm) * 8];
    }
    __builtin_amdgcn_s_setprio(1);
#pragma unroll
    for (int i = 0; i < 4; ++i)
#pragma unroll
      for (int j = 0; j < 2; ++j) {
        acc[i][j] = __builtin_amdgcn_mfma_f32_16x16x32_bf16(afh[i], bfh[j], acc[i][j], 0, 0, 0);
        acc[i][j] = __builtin_amdgcn_mfma_f32_16x16x32_bf16(afl[i], bfh[j], acc[i][j], 0, 0, 0);
        acc[i][j] = __builtin_amdgcn_mfma_f32_16x16x32_bf16(afh[i], bfl[j], acc[i][j], 0, 0, 0);
      }
    __builtin_amdgcn_s_setprio(0);
  };

  stage(0, 0);
  stage(1, 32);
  for (int k = 0; k + 64 < 256; k += 64) {
    WAITVM(6); barf();
    compute(0);
    barf();
    stage(0, k + 64);
    WAITVM(6); barf();
    compute(1);
    barf();
    stage(1, k + 96);
  }
  WAITVM(6); barf();
  compute(0);
  barf();
  WAITVM(0); barf();
  compute(1);

  const int rbase = l0 + wrow + (lane >> 4) * 4;
#pragma unroll
  for (int j = 0; j < 2; ++j) {
    int col = h * 64 + wcol + j * 16 + fm;
#pragma unroll
    for (int i = 0; i < 4; ++i)
#pragma unroll
      for (int r = 0; r < 4; ++r)
        oh[(long)(b * L_ + rbase + i * 16 + r) * 1024 + col] = f2bf(acc[i][j][r]);
  }
}

// ---------------- fused: out-of-core chol (0-63) + rff(q) (64-2111) + Wo cvt
// chol v2: LDS-routed panel dataflow. Two fixed-role LDS buffers:
//   pa [256][20] = A column-panel staging (filled by previous panel's C phase
//                  for the J==p+1 column; prologue stages col 0 from global)
//   pl [256][20] = L of current panel (written by B2, read by C)
// This removes the per-panel B1 global re-read and the diag global read; C's
// global pair-loads are software-pipelined (prefetch next pi while computing).
// Row stride 20 floats keeps rows 16B-aligned for ds_read_b128.
__global__ __launch_bounds__(512) void chol_rffq_wo_kernel(
    float* __restrict__ Gw,
    const float* __restrict__ qsrc,
    const float* __restrict__ rffW, const float* __restrict__ rffb,
    u16* __restrict__ ph, u16* __restrict__ pl_out,
    const float* __restrict__ Wo, u16* __restrict__ wo_hi)
{
  extern __shared__ float sm[];
  const int bx = blockIdx.x;
  const int tid = threadIdx.x;

  if (bx < 64) {
    float* pa   = sm;            // [256][20] = 5120 floats
    float* plds = sm + 5120;     // [256][20] = 5120 floats
    float* invD = sm + 10240;    // [16][20]  = 320 floats
    float* Gb = Gw + (long)bx * 65536;

    // prologue: stage A(:, col-block 0) into pa
    for (int f = tid; f < 4096; f += 512) {
      int rr = f >> 4, cc = f & 15;
      pa[rr * 20 + cc] = Gb[rr * 256 + cc];
    }
    __syncthreads();

    for (int p = 0; p < 16; ++p) {
      // A: wave 0 factors diag block (from pa LDS), computes invD
      if (tid < 64) {
        const int i = tid & 15;
        float r[16];
#pragma unroll
        for (int k = 0; k < 16; ++k) r[k] = pa[(16 * p + i) * 20 + k];
        r[i] += RIDGE_;
#pragma unroll
        for (int j = 0; j < 16; ++j) {
          float dj = __shfl(r[j], j);
          float dinv = 1.0f / sqrtf(dj);
          r[j] *= dinv;
          float Lij = r[j];
#pragma unroll
          for (int k = j + 1; k < 16; ++k) {
            float Lkj = __shfl(r[j], k);
            r[k] = fmaf(-Lij, Lkj, r[k]);
          }
        }
        float x[16];
#pragma unroll
        for (int j = 0; j < 16; ++j) {
          float s = (i == j) ? 1.0f : 0.0f;
#pragma unroll
          for (int k = 0; k < j; ++k) {
            float Ljk = __shfl(r[k], j);
            s = fmaf(-Ljk, x[k], s);
          }
          float Ljj = __shfl(r[j], j);
          x[j] = s / Ljj;
        }
        if (tid < 16) {
#pragma unroll
          for (int j = 0; j < 16; ++j) {
            invD[j * 20 + tid] = x[j];
            Gb[(16 * p + j) * 256 + 16 * p + tid] = x[j];  // diag slot <- invD
          }
        }
      }
      __syncthreads();

      const int nIb = 15 - p;
      if (nIb == 0) break;
      const int nrows = nIb * 16;
      const int r0 = 16 * (p + 1);

      // B2: L(I,p) = A(I,p) * invD^T  (pa -> plds + G, single pass)
#pragma unroll
      for (int s = 0; s < 8; ++s) {
        int f = tid + s * 512;
        if (f < nrows * 16) {
          int rr = f >> 4, j = f & 15;
          const float* arow = &pa[(r0 + rr) * 20];
          const float* dcol = &invD[j * 20];
          float s2 = 0.f;
#pragma unroll
          for (int k4 = 0; k4 < 16; k4 += 4) {
            float4 a4 = *(const float4*)&arow[k4];
            float4 d4 = *(const float4*)&dcol[k4];
            s2 = fmaf(a4.x, d4.x, s2);
            s2 = fmaf(a4.y, d4.y, s2);
            s2 = fmaf(a4.z, d4.z, s2);
            s2 = fmaf(a4.w, d4.w, s2);
          }
          plds[(r0 + rr) * 20 + j] = s2;
          Gb[(long)(r0 + rr) * 256 + 16 * p + j] = s2;
        }
      }
      __syncthreads();

      // C: trailing update; J == p+1 column goes to pa (next panel's A),
      // other columns read+write global. Pair loads software-pipelined.
      const int npairs = nIb * (nIb + 1) / 2;
      const int g = tid >> 4, t = tid & 15;
      const int tx = t & 3, ty = t >> 2;

      int IA = 0, JA = 0;
      float c4a[4][4];
      bool va = g < npairs;
      if (va) {
        int a = 0; while ((a + 1) * (a + 2) / 2 <= g) ++a;
        int b2 = g - a * (a + 1) / 2;
        IA = p + 1 + a; JA = p + 1 + b2;
#pragma unroll
        for (int ii = 0; ii < 4; ++ii) {
          float4 cv = *(const float4*)&Gb[(long)(16 * IA + 4 * ty + ii) * 256 + 16 * JA + 4 * tx];
          c4a[ii][0] = cv.x; c4a[ii][1] = cv.y; c4a[ii][2] = cv.z; c4a[ii][3] = cv.w;
        }
      }
      for (int pi0 = 0; pi0 < npairs; pi0 += 32) {
        // prefetch next pair's C block
        int IB = 0, JB = 0;
        float c4b[4][4];
        int piB = pi0 + 32 + g;
        bool vb = piB < npairs;
        if (vb) {
          int a = 0; while ((a + 1) * (a + 2) / 2 <= piB) ++a;
          int b2 = piB - a * (a + 1) / 2;
          IB = p + 1 + a; JB = p + 1 + b2;
#pragma unroll
          for (int ii = 0; ii < 4; ++ii) {
            float4 cv = *(const float4*)&Gb[(long)(16 * IB + 4 * ty + ii) * 256 + 16 * JB + 4 * tx];
            c4b[ii][0] = cv.x; c4b[ii][1] = cv.y; c4b[ii][2] = cv.z; c4b[ii][3] = cv.w;
          }
        }
        if (va) {
#pragma unroll
          for (int k4 = 0; k4 < 16; k4 += 4) {
            float4 a4[4], b4[4];
#pragma unroll
            for (int ii = 0; ii < 4; ++ii)
              a4[ii] = *(const float4*)&plds[(16 * IA + 4 * ty + ii) * 20 + k4];
#pragma unroll
            for (int jj = 0; jj < 4; ++jj)
              b4[jj] = *(const float4*)&plds[(16 * JA + 4 * tx + jj) * 20 + k4];
#pragma unroll
            for (int ii = 0; ii < 4; ++ii)
#pragma unroll
              for (int jj = 0; jj < 4; ++jj) {
                c4a[ii][jj] = fmaf(-a4[ii].x, b4[jj].x, c4a[ii][jj]);
                c4a[ii][jj] = fmaf(-a4[ii].y, b4[jj].y, c4a[ii][jj]);
                c4a[ii][jj] = fmaf(-a4[ii].z, b4[jj].z, c4a[ii][jj]);
                c4a[ii][jj] = fmaf(-a4[ii].w, b4[jj].w, c4a[ii][jj]);
              }
          }
          if (JA == p + 1) {
            // route to pa: next panel's A column (global copy is dead)
#pragma unroll
            for (int ii = 0; ii < 4; ++ii) {
              float4 cv = {c4a[ii][0], c4a[ii][1], c4a[ii][2], c4a[ii][3]};
              *(float4*)&pa[(16 * IA + 4 * ty + ii) * 20 + 4 * tx] = cv;
            }
          } else {
#pragma unroll
            for (int ii = 0; ii < 4; ++ii) {
              float4 cv = {c4a[ii][0], c4a[ii][1], c4a[ii][2], c4a[ii][3]};
              *(float4*)&Gb[(long)(16 * IA + 4 * ty + ii) * 256 + 16 * JA + 4 * tx] = cv;
            }
          }
        }
        // roll pipeline
        va = vb; IA = IB; JA = JB;
#pragma unroll
        for (int ii = 0; ii < 4; ++ii)
#pragma unroll
          for (int jj = 0; jj < 4; ++jj) c4a[ii][jj] = c4b[ii][jj];
      }
      __syncthreads();
    }
  } else if (bx < 64 + 2048) {
    // ---------- RFF(q) -> phiq bf16 hi/lo, 64 rows/block ----------
    const int id = bx - 64;
    const int l0 = (id & 31) * 64;
    const int h = (id >> 5) & 15;
    const int b = id >> 9;
    float* w_lds = sm;                // [64][132] = 8448
    float* x_lds = sm + 8448;         // [64][68]  = 4352
    float* b_lds = sm + 12800;        // [128]

    const float* wsrc = rffW + h * 8192;
    for (int f = tid * 4; f < 8192; f += 2048) {
      int d = f >> 7, m = f & 127;
      *(float4*)&w_lds[d * 132 + m] = *(const float4*)&wsrc[f];
    }
    if (tid < 128) b_lds[tid] = rffb[h * 128 + tid];
    {
      int r = tid >> 3, c0 = (tid & 7) * 8;
      const float* srow = qsrc + (long)(b * L_ + l0 + r) * 1024 + h * VD_ + c0;
      *(float4*)&x_lds[r * 68 + c0 + 0] = *(const float4*)(srow + 0);
      *(float4*)&x_lds[r * 68 + c0 + 4] = *(const float4*)(srow + 4);
    }
    __syncthreads();

    const int sub = tid >> 8;          // 0..1 -> row half
    const int t = tid & 255;
    const int ty = t >> 4, tx = t & 15;
    const int rrow = sub * 32 + 2 * ty;  // 2 rows per thread
    float acc[2][8];
    {
      float4 bb0 = *(const float4*)&b_lds[4 * tx];
      float4 bb1 = *(const float4*)&b_lds[4 * tx + 64];
#pragma unroll
      for (int i = 0; i < 2; ++i) {
        acc[i][0] = bb0.x; acc[i][1] = bb0.y; acc[i][2] = bb0.z; acc[i][3] = bb0.w;
        acc[i][4] = bb1.x; acc[i][5] = bb1.y; acc[i][6] = bb1.z; acc[i][7] = bb1.w;
      }
    }
#pragma unroll 8
    for (int kk = 0; kk < 64; ++kk) {
      float4 w0 = *(const float4*)&w_lds[kk * 132 + 4 * tx];
      float4 w1 = *(const float4*)&w_lds[kk * 132 + 4 * tx + 64];
      float xv[2];
#pragma unroll
      for (int i = 0; i < 2; ++i) xv[i] = x_lds[(rrow + i) * 68 + kk];
#pragma unroll
      for (int i = 0; i < 2; ++i) {
        acc[i][0] = fmaf(xv[i], w0.x, acc[i][0]);
        acc[i][1] = fmaf(xv[i], w0.y, acc[i][1]);
        acc[i][2] = fmaf(xv[i], w0.z, acc[i][2]);
        acc[i][3] = fmaf(xv[i], w0.w, acc[i][3]);
        acc[i][4] = fmaf(xv[i], w1.x, acc[i][4]);
        acc[i][5] = fmaf(xv[i], w1.y, acc[i][5]);
        acc[i][6] = fmaf(xv[i], w1.z, acc[i][6]);
        acc[i][7] = fmaf(xv[i], w1.w, acc[i][7]);
      }
    }
#pragma unroll
    for (int i = 0; i < 2; ++i) {
      int l = l0 + rrow + i;
      float4 c0, c1, s0, s1;
      float sv, cv;
      sincosf(acc[i][0], &sv, &cv); c0.x = cv * SCALE_; s0.x = sv * SCALE_;
      sincosf(acc[i][1], &sv, &cv); c0.y = cv * SCALE_; s0.y = sv * SCALE_;
      sincosf(acc[i][2], &sv, &cv); c0.z = cv * SCALE_; s0.z = sv * SCALE_;
      sincosf(acc[i][3], &sv, &cv); c0.w = cv * SCALE_; s0.w = sv * SCALE_;
      sincosf(acc[i][4], &sv, &cv); c1.x = cv * SCALE_; s1.x = sv * SCALE_;
      sincosf(acc[i][5], &sv, &cv); c1.y = cv * SCALE_; s1.y = sv * SCALE_;
      sincosf(acc[i][6], &sv, &cv); c1.z = cv * SCALE_; s1.z = sv * SCALE_;
      sincosf(acc[i][7], &sv, &cv); c1.w = cv * SCALE_; s1.w = sv * SCALE_;
      long base = ((long)(b * H_ + h) * L_ + l) * M2_;
      ushort4 hv; float4 r4;
      split4(c0, &hv, &r4);
      *(ushort4*)&ph[base + 4 * tx] = hv;
      *(ushort4*)&pl_out[base + 4 * tx] = (ushort4){f2bf(r4.x), f2bf(r4.y), f2bf(r4.z), f2bf(r4.w)};
      split4(c1, &hv, &r4);
      *(ushort4*)&ph[base + 64 + 4 * tx] = hv;
      *(ushort4*)&pl_out[base + 64 + 4 * tx] = (ushort4){f2bf(r4.x), f2bf(r4.y), f2bf(r4.z), f2bf(r4.w)};
      split4(s0, &hv, &r4);
      *(ushort4*)&ph[base + 128 + 4 * tx] = hv;
      *(ushort4*)&pl_out[base + 128 + 4 * tx] = (ushort4){f2bf(r4.x), f2bf(r4.y), f2bf(r4.z), f2bf(r4.w)};
      split4(s1, &hv, &r4);
      *(ushort4*)&ph[base + 192 + 4 * tx] = hv;
      *(ushort4*)&pl_out[base + 192 + 4 * tx] = (ushort4){f2bf(r4.x), f2bf(r4.y), f2bf(r4.z), f2bf(r4.w)};
    }
  } else {
    // ---------- Wo -> bf16 ----------
    const int id2 = bx - (64 + 2048);
    int idx = id2 * 512 + tid;
    for (int i = idx; i < 262144; i += 65536) {
      float4 f = ((const float4*)Wo)[i];
      ushort4 hv = {f2bf(f.x), f2bf(f.y), f2bf(f.z), f2bf(f.w)};
      ((ushort4*)wo_hi)[i] = hv;
    }
  }
}

// ---------------- blocked triangular solves (dense L/invD in G) -------------
__global__ __launch_bounds__(256) void tri_solve_kernel(
    const float* __restrict__ Gw, const float* __restrict__ T,
    u16* __restrict__ wth, u16* __restrict__ wtl)
{
  __shared__ float Y[256 * 17];
  __shared__ float tmp[16 * 17];
  const int bh = blockIdx.y;
  const int d0 = blockIdx.x * 16;
  const int tid = threadIdx.x;
  const int i = tid >> 4, d = tid & 15;
  const float* Gb = Gw + (long)bh * 65536;
  const float* Tb = T + (long)bh * 16384;

  for (int r = i; r < 256; r += 16) Y[r * 17 + d] = Tb[r * 64 + d0 + d];
  __syncthreads();

  for (int J = 0; J < 16; ++J) {
    float acc = Y[(J * 16 + i) * 17 + d];
    for (int c = 0; c < J; ++c) {
      const float* Lblk = &Gb[(long)(16 * J + i) * 256 + 16 * c];
#pragma unroll
      for (int k = 0; k < 16; k += 4) {
        float4 l4 = *(const float4*)&Lblk[k];
        acc = fmaf(-l4.x, Y[(c * 16 + k + 0) * 17 + d], acc);
        acc = fmaf(-l4.y, Y[(c * 16 + k + 1) * 17 + d], acc);
        acc = fmaf(-l4.z, Y[(c * 16 + k + 2) * 17 + d], acc);
        acc = fmaf(-l4.w, Y[(c * 16 + k + 3) * 17 + d], acc);
      }
    }
    tmp[i * 17 + d] = acc;
    __syncthreads();
    const float* invD = &Gb[(long)(16 * J + i) * 256 + 16 * J];
    float y = 0.f;
#pragma unroll
    for (int k = 0; k < 16; ++k) y = fmaf(invD[k], tmp[k * 17 + d], y);
    Y[(J * 16 + i) * 17 + d] = y;
    __syncthreads();
  }

  for (int J = 15; J >= 0; --J) {
    float acc = Y[(J * 16 + i) * 17 + d];
    for (int I = J + 1; I < 16; ++I) {
#pragma unroll
      for (int k = 0; k < 16; ++k)
        acc = fmaf(-Gb[(long)(16 * I + k) * 256 + 16 * J + i], Y[(I * 16 + k) * 17 + d], acc);
    }
    tmp[i * 17 + d] = acc;
    __syncthreads();
    float w = 0.f;
#pragma unroll
    for (int k = 0; k < 16; ++k)
      w = fmaf(Gb[(long)(16 * J + k) * 256 + 16 * J + i], tmp[k * 17 + d], w);
    Y[(J * 16 + i) * 17 + d] = w;
    __syncthreads();
  }

  for (int f = tid; f < 16 * 256; f += 256) {
    int dc = f >> 8, m = f & 255;
    float val = Y[m * 17 + dc];
    u16 h = f2bf(val);
    long o = (long)bh * 16384 + (long)(d0 + dc) * 256 + m;
    wth[o] = h;
    wtl[o] = f2bf(val - bf2f(h));
  }
}

__global__ void ws_too_small_kernel(float* out) { out[0] = 12345.0f; }

extern "C" void kernel_launch(void* const* d_in, const int* in_sizes, int n_in,
                              void* d_out, int out_size, void* d_ws, size_t ws_size,
                              hipStream_t stream) {
  const float* x    = (const float*)d_in[0];
  const float* mask = (const float*)d_in[2];
  const float* Wq   = (const float*)d_in[3];
  const float* Wk   = (const float*)d_in[4];
  const float* Wv   = (const float*)d_in[5];
  const float* Wo   = (const float*)d_in[6];
  const float* bo   = (const float*)d_in[7];
  const float* rffW = (const float*)d_in[8];
  const float* rffb = (const float*)d_in[9];
  float* out = (float*)d_out;
  float* ws  = (float*)d_ws;

  const size_t needed = 58720256UL * 4UL;  // 234.9 MB
  if (ws_size < needed) {
    ws_too_small_kernel<<<1, 1, 0, stream>>>(out);
    return;
  }
  // region A [0, 8.4M): q fp32 -> oh bf16 after rff(q)
  float* q = ws;
  u16* oh_bf = (u16*)ws;
  // region B [8.4M, 16.7M): k fp32 -> T(1M)+G(4.2M) after reduce (kbuf dead)
  float* kbuf = ws + 8388608;
  float* T    = ws + 8388608;
  float* G    = ws + 9437184;
  // region big [16.7M, 50.3M):
  u16* big16 = (u16*)(ws + 16777216);
  u16* x_hi = big16;
  u16* x_lo = big16 + 8388608;
  u16* w_hi = big16 + 16777216;
  u16* w_lo = big16 + 19922944;
  u16* pk_hi = big16;                      // [0, 20971520) u16
  u16* pk_lo = big16 + 20971520;           // [20971520, 41943040) u16
  float* Gp = ws + 37748736;               // 2 x 4194304 floats
  float* Tp = ws + 46137344;               // 2 x 1048576 floats
  u16* phiq_hi = big16;                    // after reduce, whole big region
  u16* phiq_lo = big16 + 33554432;         // (overlaps Gp/Tp -> reduce first!)
  // region D [50.3M, 58.7M): v fp32 -> wt/wo bf16
  float* v = ws + 50331648;
  u16* wt_hi = (u16*)(ws + 50331648);
  u16* wt_lo = wt_hi + 1048576;
  u16* wo_hi = wt_hi + 2097152;

  hipFuncSetAttribute((const void*)chol_rffq_wo_kernel,
                      hipFuncAttributeMaxDynamicSharedMemorySize, 51712);

  dim3 blk(256);

  // 1: convert x and W to bf16 hi/lo
  cvt_split_kernel<<<8192, blk, 0, stream>>>(x, x_hi, x_lo, 2097152);
  cvt_split_kernel<<<1024, blk, 0, stream>>>(Wq, w_hi,           w_lo,           262144);
  cvt_split_kernel<<<1024, blk, 0, stream>>>(Wk, w_hi + 1048576, w_lo + 1048576, 262144);
  cvt_split_kernel<<<1024, blk, 0, stream>>>(Wv, w_hi + 2097152, w_lo + 2097152, 262144);

  // 2: QKV — qk 3-pass (uniform) + v hi-only
  mfma_qk3<<<dim3(16, 64), blk, 0, stream>>>(x_hi, x_lo, w_hi, w_lo, q, kbuf);
  mfma_nt<<<dim3(8, 64), blk, 0, stream>>>(x_hi, w_hi + 2097152, v,
                                           1024, 1024, 1024, 1024, nullptr, nullptr);

  // 3: two bh-halves: rff(k)->pkT, vT->pkT, [G-lower|T] MFMA (K-split x2)
  for (int half = 0; half < 2; ++half) {
    int b0 = half * 2, bh0 = half * 32;
    rff_k_t<<<dim3(32, 16, 2), blk, 0, stream>>>(kbuf, mask, rffW, rffb, pk_hi, pk_lo, b0);
    vt_kernel<<<dim3(16, 32), blk, 0, stream>>>(v, mask, pk_hi, pk_lo, b0);
    mfma_gt<<<dim3(8, 2, 32), blk, 0, stream>>>(pk_hi, pk_lo, Gp, Tp, bh0);
  }

  // 4: reduce partials -> final G, T (MUST precede phiq write: aliasing)
  reduce_gt_kernel<<<5120, blk, 0, stream>>>(Gp, G, Tp, T);

  // 5: fused out-of-core chol (in-place on G) + rff(q)->phiq + Wo cvt
  chol_rffq_wo_kernel<<<dim3(64 + 2048 + 128), dim3(512), 51712, stream>>>(
      G, q, rffW, rffb, phiq_hi, phiq_lo, Wo, wo_hi);

  // 6: tri solves (dense L/invD from G) -> wt bf16 hi/lo
  tri_solve_kernel<<<dim3(4, 64), dim3(256), 0, stream>>>(G, T, wt_hi, wt_lo);

  // 7: out-heads MFMA (bf16 output)
  mfma_out_k<<<dim3(16, 64), blk, 0, stream>>>(phiq_hi, phiq_lo, wt_hi, wt_lo, oh_bf);

  // 8: Wo projection (bf16 MFMA) with bias+mask epilogue
  mfma_nt<<<dim3(8, 64), blk, 0, stream>>>(oh_bf, wo_hi, out, 1024, 1024, 1024, 1024, bo, mask);
}